// Round 10
// baseline (296.147 us; speedup 1.0000x reference)
//
#include <hip/hip_runtime.h>

typedef unsigned long long u64;
typedef __attribute__((ext_vector_type(8))) short s8v;   // 8 bf16 = 4 VGPRs (MFMA A/B frag)
typedef __attribute__((ext_vector_type(4))) float f4v;   // MFMA C/D frag

__device__ __constant__ int c_pi[10]   = {0,1,2,3,0,1,2,3,3,3};
__device__ __constant__ int c_pj[10]   = {0,1,2,3,3,3,3,0,1,2};
__device__ __constant__ int c_dri[10]  = {1,5,8,10,4,7,9,4,7,9};
__device__ __constant__ int c_diag[10] = {1,1,1,1,0,0,0,0,0,0};
__device__ __constant__ int c_src[16]  = {-1,7,8,9,  4,-1,8,9,  5,5,-1,9,  6,6,6,-1};

// round-to-nearest bf16
__device__ inline unsigned short bf16rn(float v) {
  unsigned int u = __float_as_uint(v);
  unsigned int r = u + 0x7fffu + ((u >> 16) & 1u);
  return (unsigned short)(r >> 16);
}
__device__ inline void split2(float v, short& h, short& l) {
  unsigned short hs = bf16rn(v);
  float fh = __uint_as_float(((unsigned int)hs) << 16);
  h = (short)hs;
  l = (short)bf16rn(v - fh);
}
__device__ inline void split3(float v, short& h, short& m, short& l) {
  unsigned short hs = bf16rn(v);
  float fh = __uint_as_float(((unsigned int)hs) << 16);
  float r1 = v - fh;
  unsigned short ms = bf16rn(r1);
  float fm = __uint_as_float(((unsigned int)ms) << 16);
  h = (short)hs; m = (short)ms;
  l = (short)bf16rn(r1 - fm);
}

// fragment-major pack offset: row r, k-index k, KC = K/32 chunks
__device__ inline size_t packoff(int row, int k, int KC) {
  int T = row >> 4, rr = row & 15;
  int c = k >> 5, q = (k >> 3) & 3, j = k & 7;
  return (((size_t)T*KC + c)*64 + q*16 + rr)*8 + j;
}

// ---------- 1. center+normalize rows -> 3 base split packs; feature pack ----------
__global__ __launch_bounds__(128) void k_rownorm(const float* __restrict__ f,
                                                 short* __restrict__ yhP, short* __restrict__ ymP,
                                                 short* __restrict__ ylP,
                                                 short* __restrict__ fPh, short* __restrict__ fPl) {
  int r = blockIdx.x, t = threadIdx.x;
  __shared__ float red[128];
  float v = f[r*128 + t];
  red[t] = v; __syncthreads();
  for (int s = 64; s > 0; s >>= 1) { if (t < s) red[t] += red[t+s]; __syncthreads(); }
  float mean = red[0] * (1.0f/128.0f);
  __syncthreads();
  float xc = v - mean;
  red[t] = xc*xc; __syncthreads();
  for (int s = 64; s > 0; s >>= 1) { if (t < s) red[t] += red[t+s]; __syncthreads(); }
  float inv = 1.0f / sqrtf(red[0]);
  short h, m, l;
  split3(xc*inv, h, m, l);
  size_t o = packoff(r, t, 4);
  yhP[o] = h; ymP[o] = m; ylP[o] = l;
  short fh, fl; split2(v, fh, fl);
  fPh[o] = fh; fPl[o] = fl;
}

// ---------- 2. correlation bit blocks: base-pack GEMM, 6 chain combos from registers ----------
__global__ __launch_bounds__(256) void k_corr3(const short* __restrict__ yhP, const short* __restrict__ ymP,
                                               const short* __restrict__ ylP,
                                               const float* __restrict__ sparse, u64* __restrict__ bits) {
  int z = blockIdx.z;
  int bx = blockIdx.x, by = blockIdx.y;
  int dg = c_diag[z];
  if (dg && by < bx) return;
  int a0 = c_pi[z]*1024 + bx*64;
  int b0 = c_pj[z]*1024 + by*64;
  int tid = threadIdx.x, lane = tid & 63, wid = tid >> 6;
  int quad = lane >> 4, l15 = lane & 15;
  const s8v* AH = (const s8v*)yhP + ((size_t)((a0>>4) + wid))*4*64 + lane;
  const s8v* AM = (const s8v*)ymP + ((size_t)((a0>>4) + wid))*4*64 + lane;
  const s8v* AL = (const s8v*)ylP + ((size_t)((a0>>4) + wid))*4*64 + lane;
  const s8v* BH = (const s8v*)yhP + ((size_t)(b0>>4))*4*64 + lane;
  const s8v* BM = (const s8v*)ymP + ((size_t)(b0>>4))*4*64 + lane;
  const s8v* BL = (const s8v*)ylP + ((size_t)(b0>>4))*4*64 + lane;
  f4v acc[4];
  #pragma unroll
  for (int i = 0; i < 4; ++i) { acc[i][0]=0.f; acc[i][1]=0.f; acc[i][2]=0.f; acc[i][3]=0.f; }
  for (int c = 0; c < 4; ++c) {
    s8v a_h = AH[c*64];
    s8v a_m = AM[c*64];
    s8v a_l = AL[c*64];
    #pragma unroll
    for (int nt = 0; nt < 4; ++nt) {
      s8v b_h = BH[(nt*4 + c)*64];
      s8v b_m = BM[(nt*4 + c)*64];
      s8v b_l = BL[(nt*4 + c)*64];
      acc[nt] = __builtin_amdgcn_mfma_f32_16x16x32_bf16(a_h, b_h, acc[nt], 0, 0, 0);
      acc[nt] = __builtin_amdgcn_mfma_f32_16x16x32_bf16(a_m, b_m, acc[nt], 0, 0, 0);
      acc[nt] = __builtin_amdgcn_mfma_f32_16x16x32_bf16(a_h, b_m, acc[nt], 0, 0, 0);
      acc[nt] = __builtin_amdgcn_mfma_f32_16x16x32_bf16(a_m, b_h, acc[nt], 0, 0, 0);
      acc[nt] = __builtin_amdgcn_mfma_f32_16x16x32_bf16(a_h, b_l, acc[nt], 0, 0, 0);
      acc[nt] = __builtin_amdgcn_mfma_f32_16x16x32_bf16(a_l, b_h, acc[nt], 0, 0, 0);
    }
  }
  __shared__ unsigned char lby[64*68];
  float sv = sparse[c_dri[z]];
  float dr = 1.0f / (1.0f + expf(-sv));
  #pragma unroll
  for (int nt = 0; nt < 4; ++nt) {
    #pragma unroll
    for (int reg = 0; reg < 4; ++reg) {
      int lr = wid*16 + quad*4 + reg;
      int lc = nt*16 + l15;
      int ga = bx*64 + lr, gb = by*64 + lc;
      int on = (fabsf(acc[nt][reg]) > dr) && !(dg && (ga == gb));
      lby[lr*68 + lc] = (unsigned char)on;
    }
  }
  __syncthreads();
  if (tid < 64) {
    u64 w = 0;
    for (int c2 = 0; c2 < 64; ++c2) w |= ((u64)lby[tid*68 + c2]) << c2;
    bits[z*16384 + (bx*64 + tid)*16 + by] = w;
    if (dg && bx != by) {
      u64 wt = 0;
      for (int c2 = 0; c2 < 64; ++c2) wt |= ((u64)lby[c2*68 + tid]) << c2;
      bits[z*16384 + (by*64 + tid)*16 + bx] = wt;
    }
  }
}

// ---------- 3. mask rows: 8-deep pipelined bit-walk ----------
__global__ __launch_bounds__(64) void k_maskrows(const u64* __restrict__ bits, u64* __restrict__ mask,
                                                 u64* __restrict__ mask_wm, int* __restrict__ deg2,
                                                 u64* __restrict__ cmask) {
  int u = blockIdx.x;
  int i = u >> 10, a = u & 1023;
  int t = threadIdx.x;
  __shared__ u64 drow[16];
  if (t < 16) drow[t] = bits[i*16384 + a*16 + t];
  __syncthreads();
  int j = t >> 4, wl = t & 15;
  u64 out;
  if (j == i) {
    out = drow[wl];
  } else {
    const u64* S = bits + c_src[i*4 + j]*16384;
    out = 0;
    for (int w2 = 0; w2 < 16; ++w2) {
      u64 m = drow[w2];
      const u64* base = S + (size_t)w2*1024 + wl;
      while (m) {
        u64 v0 = 0, v1 = 0, v2 = 0, v3 = 0, v4 = 0, v5 = 0, v6 = 0, v7 = 0;
        int b = __builtin_ctzll(m); m &= m - 1; v0 = base[b*16];
        if (m) { b = __builtin_ctzll(m); m &= m - 1; v1 = base[b*16]; }
        if (m) { b = __builtin_ctzll(m); m &= m - 1; v2 = base[b*16]; }
        if (m) { b = __builtin_ctzll(m); m &= m - 1; v3 = base[b*16]; }
        if (m) { b = __builtin_ctzll(m); m &= m - 1; v4 = base[b*16]; }
        if (m) { b = __builtin_ctzll(m); m &= m - 1; v5 = base[b*16]; }
        if (m) { b = __builtin_ctzll(m); m &= m - 1; v6 = base[b*16]; }
        if (m) { b = __builtin_ctzll(m); m &= m - 1; v7 = base[b*16]; }
        out |= ((v0 | v1) | (v2 | v3)) | ((v4 | v5) | (v6 | v7));
      }
    }
  }
  mask[(size_t)u*64 + t] = out;
  mask_wm[(size_t)t*4096 + u] = out;
  u64 bal = __ballot(out != 0ULL);
  if (t == 0 && bal) atomicOr((unsigned long long*)&cmask[64 + (u >> 6)], bal);
  int cnt = __popcll(out);
  for (int off = 32; off > 0; off >>= 1) cnt += __shfl_down(cnt, off);
  if (t == 0) deg2[u] = cnt;
}

// ---------- 4. bit transpose -> maskT word-major + deg1 atomics + cmask[g=0] ----------
__global__ __launch_bounds__(256) void k_bittrans2(const u64* __restrict__ mask, u64* __restrict__ wmT,
                                                   int* __restrict__ deg1, u64* __restrict__ cmask) {
  __shared__ u64 tile[4096];   // 64 rows x 64 words = 32 KB
  int tI = blockIdx.x, tid = threadIdx.x;
  for (int e = tid; e < 4096; e += 256) tile[e] = mask[(size_t)tI*4096 + e];
  __syncthreads();
  int wv = tid >> 6, lane = tid & 63;
  int tJ0 = blockIdx.y*16;
  for (int j = 0; j < 4; ++j) {
    int tJ = tJ0 + wv*4 + j;
    u64 o = 0;
    #pragma unroll 8
    for (int k = 0; k < 64; ++k) o |= ((tile[k*64 + tJ] >> lane) & 1ULL) << k;
    wmT[(size_t)tI*4096 + tJ*64 + lane] = o;
    atomicAdd(&deg1[tJ*64 + lane], __popcll(o));
    u64 bal = __ballot(o != 0ULL);
    if (lane == 0 && bal) atomicOr((unsigned long long*)&cmask[tJ], 1ULL << tI);
  }
}

// ---------- 5. weight prep (both layers in one dispatch) ----------
__global__ __launch_bounds__(256) void k_prepWTall(const float* __restrict__ wAC1, const float* __restrict__ wCA1,
                                                   const float* __restrict__ wAC2, const float* __restrict__ wCA2,
                                                   short* __restrict__ w1h, short* __restrict__ w1l,
                                                   short* __restrict__ w2h, short* __restrict__ w2l) {
  __shared__ float lds[64*65];
  int z = blockIdx.z;
  int bx = blockIdx.x;
  if (z == 0 && bx >= 2) return;
  int K = z ? 512 : 128;
  const float* Wa = z ? wAC2 : wAC1;
  const float* Wb = z ? wCA2 : wCA1;
  short* wph = z ? w2h : w1h;
  short* wpl = z ? w2l : w1l;
  int tid = threadIdx.x;
  int k0 = bx*64, n0 = blockIdx.y*64;
  const float* W = (n0 < 256) ? Wa : Wb;
  int nc0 = n0 & 255;
  for (int e = tid; e < 4096; e += 256) {
    int r = e >> 6, c = e & 63;
    lds[r*65 + c] = W[(size_t)(k0+r)*256 + nc0 + c];
  }
  __syncthreads();
  int KC = K >> 5;
  for (int e = tid; e < 4096; e += 256) {
    int j = e & 7, ln = (e >> 3) & 63, cp = (e >> 9) & 1, Tp = e >> 10;
    int q = ln >> 4, rr = ln & 15;
    float v = lds[(cp*32 + q*8 + j)*65 + (Tp*16 + rr)];
    short h, l; split2(v, h, l);
    size_t off = (((size_t)((n0>>4)+Tp)*KC + (k0>>5)+cp)*64 + ln)*8 + j;
    wph[off] = h; wpl[off] = l;
  }
}

// ---------- 6. dense GEMM + fused B-prep: Z tile + nrm-scaled frag-major BT packs ----------
__global__ __launch_bounds__(256) void k_dense3(const short* __restrict__ Ah, const short* __restrict__ Al,
                                                const short* __restrict__ Bh, const short* __restrict__ Bl,
                                                float* __restrict__ Z, int KC,
                                                const int* __restrict__ deg1, const int* __restrict__ deg2,
                                                short* __restrict__ bph, short* __restrict__ bpl) {
  __shared__ float tile[64*65];
  int tid = threadIdx.x, lane = tid & 63, wid = tid >> 6;
  int quad = lane >> 4, l15 = lane & 15;
  int m0 = blockIdx.x*64, n0 = blockIdx.y*64;
  const s8v* ah = (const s8v*)Ah + ((size_t)((m0>>4) + wid))*KC*64 + lane;
  const s8v* al = (const s8v*)Al + ((size_t)((m0>>4) + wid))*KC*64 + lane;
  const s8v* bh0 = (const s8v*)Bh + ((size_t)((n0>>4) + 0))*KC*64 + lane;
  const s8v* bh1 = (const s8v*)Bh + ((size_t)((n0>>4) + 1))*KC*64 + lane;
  const s8v* bh2 = (const s8v*)Bh + ((size_t)((n0>>4) + 2))*KC*64 + lane;
  const s8v* bh3 = (const s8v*)Bh + ((size_t)((n0>>4) + 3))*KC*64 + lane;
  const s8v* bl0 = (const s8v*)Bl + ((size_t)((n0>>4) + 0))*KC*64 + lane;
  const s8v* bl1 = (const s8v*)Bl + ((size_t)((n0>>4) + 1))*KC*64 + lane;
  const s8v* bl2 = (const s8v*)Bl + ((size_t)((n0>>4) + 2))*KC*64 + lane;
  const s8v* bl3 = (const s8v*)Bl + ((size_t)((n0>>4) + 3))*KC*64 + lane;
  f4v acc[4];
  #pragma unroll
  for (int i = 0; i < 4; ++i) { acc[i][0]=0.f; acc[i][1]=0.f; acc[i][2]=0.f; acc[i][3]=0.f; }
  for (int c = 0; c < KC; ++c) {
    s8v a_h = ah[c*64];
    s8v a_l = al[c*64];
    acc[0] = __builtin_amdgcn_mfma_f32_16x16x32_bf16(a_h, bh0[c*64], acc[0], 0, 0, 0);
    acc[0] = __builtin_amdgcn_mfma_f32_16x16x32_bf16(a_h, bl0[c*64], acc[0], 0, 0, 0);
    acc[0] = __builtin_amdgcn_mfma_f32_16x16x32_bf16(a_l, bh0[c*64], acc[0], 0, 0, 0);
    acc[1] = __builtin_amdgcn_mfma_f32_16x16x32_bf16(a_h, bh1[c*64], acc[1], 0, 0, 0);
    acc[1] = __builtin_amdgcn_mfma_f32_16x16x32_bf16(a_h, bl1[c*64], acc[1], 0, 0, 0);
    acc[1] = __builtin_amdgcn_mfma_f32_16x16x32_bf16(a_l, bh1[c*64], acc[1], 0, 0, 0);
    acc[2] = __builtin_amdgcn_mfma_f32_16x16x32_bf16(a_h, bh2[c*64], acc[2], 0, 0, 0);
    acc[2] = __builtin_amdgcn_mfma_f32_16x16x32_bf16(a_h, bl2[c*64], acc[2], 0, 0, 0);
    acc[2] = __builtin_amdgcn_mfma_f32_16x16x32_bf16(a_l, bh2[c*64], acc[2], 0, 0, 0);
    acc[3] = __builtin_amdgcn_mfma_f32_16x16x32_bf16(a_h, bh3[c*64], acc[3], 0, 0, 0);
    acc[3] = __builtin_amdgcn_mfma_f32_16x16x32_bf16(a_h, bl3[c*64], acc[3], 0, 0, 0);
    acc[3] = __builtin_amdgcn_mfma_f32_16x16x32_bf16(a_l, bh3[c*64], acc[3], 0, 0, 0);
  }
  #pragma unroll
  for (int nt = 0; nt < 4; ++nt) {
    #pragma unroll
    for (int reg = 0; reg < 4; ++reg) {
      int rl = wid*16 + quad*4 + reg;
      int cl = nt*16 + l15;
      float v = acc[nt][reg];
      Z[(size_t)(m0+rl)*512 + n0 + cl] = v;
      tile[rl*65 + cl] = v;
    }
  }
  __syncthreads();
  const int* dg = (n0 < 256) ? deg1 : deg2;
  for (int e = tid; e < 4096; e += 256) {   // pack-major write order (coalesced)
    int j = e & 7, ln = (e >> 3) & 63, cp = (e >> 9) & 1, Tp = e >> 10;
    int q = ln >> 4, rr = ln & 15;
    int krow = cp*32 + q*8 + j;             // node-local row
    int d = dg[m0 + krow];
    float nr = d > 0 ? (1.0f / sqrtf((float)d)) : 0.0f;
    float v = tile[krow*65 + (Tp*16 + rr)] * nr;
    short h, l; split2(v, h, l);
    size_t off = (((size_t)((n0>>4)+Tp)*128 + (m0>>5)+cp)*64 + ln)*8 + j;
    bph[off] = h; bpl[off] = l;
  }
}

// ---------- 7. mask GEMM v4: M=128/block (halves B L2 traffic) + fused BN partial sums ----------
__global__ __launch_bounds__(512) void k_mg4(const u64* __restrict__ wmT, const u64* __restrict__ wmR,
                                             const u64* __restrict__ cmask,
                                             const short* __restrict__ bph, const short* __restrict__ bpl,
                                             const float* __restrict__ Z,
                                             const int* __restrict__ deg1, const int* __restrict__ deg2,
                                             const float* __restrict__ biasA, const float* __restrict__ biasB,
                                             float* __restrict__ h, float* __restrict__ bnacc) {
  __shared__ s8v lut[256];   // byte -> 8 bf16 {0,1}
  __shared__ float tile[128*65];   // 33 KB
  int tid = threadIdx.x;
  if (tid < 256) {
    s8v e;
    #pragma unroll
    for (int j = 0; j < 8; ++j) e[j] = ((tid >> j) & 1) ? (short)0x3F80 : (short)0;
    lut[tid] = e;
  }
  __syncthreads();
  int g = blockIdx.z;
  const u64* wm = g ? wmR : wmT;
  u64 cm = cmask[g*64 + 2*blockIdx.x] | cmask[g*64 + 2*blockIdx.x + 1];
  int m0 = blockIdx.x*128, n0 = blockIdx.y*64;
  int lane = tid & 63, wid = tid >> 6, quad = lane >> 4, l15 = lane & 15;
  int nw = wid & 3, ks = wid >> 2;
  u64 cmw = ks ? (cm >> 32) : (cm & 0xffffffffULL);
  int kwb = ks << 5;
  int T = g*16 + (n0 >> 4) + nw;
  const s8v* BH = (const s8v*)bph + (size_t)T*128*64 + lane;
  const s8v* BL = (const s8v*)bpl + (size_t)T*128*64 + lane;
  f4v acc[8];
  #pragma unroll
  for (int i = 0; i < 8; ++i) { acc[i][0]=0.f; acc[i][1]=0.f; acc[i][2]=0.f; acc[i][3]=0.f; }
  s8v z8;
  #pragma unroll
  for (int j = 0; j < 8; ++j) z8[j] = 0;

  int kw = -1;
  u64 w0=0,w1=0,w2=0,w3=0,w4=0,w5=0,w6=0,w7=0;
  s8v b0h = z8, b0l = z8, b1h = z8, b1l = z8;
  if (cmw) {
    kw = kwb + __builtin_ctzll(cmw); cmw &= cmw - 1;
    const u64* wp = wm + (size_t)kw*4096 + m0;
    w0 = wp[l15];      w1 = wp[16 + l15]; w2 = wp[32 + l15]; w3 = wp[48 + l15];
    w4 = wp[64 + l15]; w5 = wp[80 + l15]; w6 = wp[96 + l15]; w7 = wp[112 + l15];
    b0h = BH[(kw*2)*64];   b0l = BL[(kw*2)*64];
    b1h = BH[(kw*2+1)*64]; b1l = BL[(kw*2+1)*64];
  }
  while (kw >= 0) {
    int kwn = -1;
    u64 n0w=0,n1w=0,n2w=0,n3w=0,n4w=0,n5w=0,n6w=0,n7w=0;
    s8v nb0h = z8, nb0l = z8, nb1h = z8, nb1l = z8;
    if (cmw) {                                  // prefetch next chunk (mask words + B frags)
      kwn = kwb + __builtin_ctzll(cmw); cmw &= cmw - 1;
      const u64* wp = wm + (size_t)kwn*4096 + m0;
      n0w = wp[l15];      n1w = wp[16 + l15]; n2w = wp[32 + l15]; n3w = wp[48 + l15];
      n4w = wp[64 + l15]; n5w = wp[80 + l15]; n6w = wp[96 + l15]; n7w = wp[112 + l15];
      nb0h = BH[(kwn*2)*64];   nb0l = BL[(kwn*2)*64];
      nb1h = BH[(kwn*2+1)*64]; nb1l = BL[(kwn*2+1)*64];
    }
    {
      unsigned sh = quad*8;
      s8v a0 = lut[(unsigned)(w0 >> sh) & 0xffu];
      s8v a1 = lut[(unsigned)(w1 >> sh) & 0xffu];
      s8v a2 = lut[(unsigned)(w2 >> sh) & 0xffu];
      s8v a3 = lut[(unsigned)(w3 >> sh) & 0xffu];
      s8v a4 = lut[(unsigned)(w4 >> sh) & 0xffu];
      s8v a5 = lut[(unsigned)(w5 >> sh) & 0xffu];
      s8v a6 = lut[(unsigned)(w6 >> sh) & 0xffu];
      s8v a7 = lut[(unsigned)(w7 >> sh) & 0xffu];
      acc[0] = __builtin_amdgcn_mfma_f32_16x16x32_bf16(a0, b0h, acc[0], 0, 0, 0);
      acc[0] = __builtin_amdgcn_mfma_f32_16x16x32_bf16(a0, b0l, acc[0], 0, 0, 0);
      acc[1] = __builtin_amdgcn_mfma_f32_16x16x32_bf16(a1, b0h, acc[1], 0, 0, 0);
      acc[1] = __builtin_amdgcn_mfma_f32_16x16x32_bf16(a1, b0l, acc[1], 0, 0, 0);
      acc[2] = __builtin_amdgcn_mfma_f32_16x16x32_bf16(a2, b0h, acc[2], 0, 0, 0);
      acc[2] = __builtin_amdgcn_mfma_f32_16x16x32_bf16(a2, b0l, acc[2], 0, 0, 0);
      acc[3] = __builtin_amdgcn_mfma_f32_16x16x32_bf16(a3, b0h, acc[3], 0, 0, 0);
      acc[3] = __builtin_amdgcn_mfma_f32_16x16x32_bf16(a3, b0l, acc[3], 0, 0, 0);
      acc[4] = __builtin_amdgcn_mfma_f32_16x16x32_bf16(a4, b0h, acc[4], 0, 0, 0);
      acc[4] = __builtin_amdgcn_mfma_f32_16x16x32_bf16(a4, b0l, acc[4], 0, 0, 0);
      acc[5] = __builtin_amdgcn_mfma_f32_16x16x32_bf16(a5, b0h, acc[5], 0, 0, 0);
      acc[5] = __builtin_amdgcn_mfma_f32_16x16x32_bf16(a5, b0l, acc[5], 0, 0, 0);
      acc[6] = __builtin_amdgcn_mfma_f32_16x16x32_bf16(a6, b0h, acc[6], 0, 0, 0);
      acc[6] = __builtin_amdgcn_mfma_f32_16x16x32_bf16(a6, b0l, acc[6], 0, 0, 0);
      acc[7] = __builtin_amdgcn_mfma_f32_16x16x32_bf16(a7, b0h, acc[7], 0, 0, 0);
      acc[7] = __builtin_amdgcn_mfma_f32_16x16x32_bf16(a7, b0l, acc[7], 0, 0, 0);
      sh = 32 + quad*8;
      a0 = lut[(unsigned)(w0 >> sh) & 0xffu];
      a1 = lut[(unsigned)(w1 >> sh) & 0xffu];
      a2 = lut[(unsigned)(w2 >> sh) & 0xffu];
      a3 = lut[(unsigned)(w3 >> sh) & 0xffu];
      a4 = lut[(unsigned)(w4 >> sh) & 0xffu];
      a5 = lut[(unsigned)(w5 >> sh) & 0xffu];
      a6 = lut[(unsigned)(w6 >> sh) & 0xffu];
      a7 = lut[(unsigned)(w7 >> sh) & 0xffu];
      acc[0] = __builtin_amdgcn_mfma_f32_16x16x32_bf16(a0, b1h, acc[0], 0, 0, 0);
      acc[0] = __builtin_amdgcn_mfma_f32_16x16x32_bf16(a0, b1l, acc[0], 0, 0, 0);
      acc[1] = __builtin_amdgcn_mfma_f32_16x16x32_bf16(a1, b1h, acc[1], 0, 0, 0);
      acc[1] = __builtin_amdgcn_mfma_f32_16x16x32_bf16(a1, b1l, acc[1], 0, 0, 0);
      acc[2] = __builtin_amdgcn_mfma_f32_16x16x32_bf16(a2, b1h, acc[2], 0, 0, 0);
      acc[2] = __builtin_amdgcn_mfma_f32_16x16x32_bf16(a2, b1l, acc[2], 0, 0, 0);
      acc[3] = __builtin_amdgcn_mfma_f32_16x16x32_bf16(a3, b1h, acc[3], 0, 0, 0);
      acc[3] = __builtin_amdgcn_mfma_f32_16x16x32_bf16(a3, b1l, acc[3], 0, 0, 0);
      acc[4] = __builtin_amdgcn_mfma_f32_16x16x32_bf16(a4, b1h, acc[4], 0, 0, 0);
      acc[4] = __builtin_amdgcn_mfma_f32_16x16x32_bf16(a4, b1l, acc[4], 0, 0, 0);
      acc[5] = __builtin_amdgcn_mfma_f32_16x16x32_bf16(a5, b1h, acc[5], 0, 0, 0);
      acc[5] = __builtin_amdgcn_mfma_f32_16x16x32_bf16(a5, b1l, acc[5], 0, 0, 0);
      acc[6] = __builtin_amdgcn_mfma_f32_16x16x32_bf16(a6, b1h, acc[6], 0, 0, 0);
      acc[6] = __builtin_amdgcn_mfma_f32_16x16x32_bf16(a6, b1l, acc[6], 0, 0, 0);
      acc[7] = __builtin_amdgcn_mfma_f32_16x16x32_bf16(a7, b1h, acc[7], 0, 0, 0);
      acc[7] = __builtin_amdgcn_mfma_f32_16x16x32_bf16(a7, b1l, acc[7], 0, 0, 0);
    }
    kw = kwn;
    w0=n0w; w1=n1w; w2=n2w; w3=n3w; w4=n4w; w5=n5w; w6=n6w; w7=n7w;
    b0h = nb0h; b0l = nb0l; b1h = nb1h; b1l = nb1l;
  }
  // combine K-halves through LDS; epilogue + BN partial sums by ks==0 waves
  int nl = nw*16 + l15;
  if (ks == 1) {
    #pragma unroll
    for (int mf = 0; mf < 8; ++mf) {
      #pragma unroll
      for (int reg = 0; reg < 4; ++reg)
        tile[(mf*16 + quad*4 + reg)*65 + nl] = acc[mf][reg];
    }
  }
  __syncthreads();
  if (ks == 0) {
    int n = n0 + nl;
    const int* dgp = g ? deg2 : deg1;
    float bn = (g ? biasB : biasA)[n];
    int zoff = g*256;
    float sv = 0.0f, qv = 0.0f;
    #pragma unroll
    for (int mf = 0; mf < 8; ++mf) {
      #pragma unroll
      for (int reg = 0; reg < 4; ++reg) {
        int v = m0 + mf*16 + quad*4 + reg;
        float s = acc[mf][reg] + tile[(mf*16 + quad*4 + reg)*65 + nl];
        int d = dgp[v];
        float sfac = 0.0f;
        if (d > 0) { float df = (float)d; sfac = (1.0f / sqrtf(df)) / df; }
        float val = Z[(size_t)v*512 + zoff + n] + sfac*s + bn;
        val = fmaxf(val, 0.0f);
        h[(size_t)v*512 + zoff + n] = val;
        sv += val; qv += val*val;
      }
    }
    // reduce over the 4 quads sharing column n
    sv += __shfl_down(sv, 32); qv += __shfl_down(qv, 32);
    sv += __shfl_down(sv, 16); qv += __shfl_down(qv, 16);
    if (quad == 0) {
      int col = zoff + n;
      atomicAdd(&bnacc[col*2 + 0], sv);
      atomicAdd(&bnacc[col*2 + 1], qv);
    }
  }
}

// ---------- 8. BN apply + split to frag-major hn packs (K=512) ----------
__global__ __launch_bounds__(256) void k_bnapply_split(const float* __restrict__ h, const float* __restrict__ acc,
                                                       const float* __restrict__ gamma, const float* __restrict__ beta,
                                                       short* __restrict__ hPh, short* __restrict__ hPl) {
  int i = blockIdx.x*256 + threadIdx.x;       // 524288 float4s
  float4 v = ((const float4*)h)[i];
  int r = i >> 7;
  int colb = (i & 127) * 4;
  float vv[4] = {v.x, v.y, v.z, v.w};
  short4 hh, ll;
  short* hp = (short*)&hh; short* lp = (short*)&ll;
  #pragma unroll
  for (int j = 0; j < 4; ++j) {
    int col = colb + j;
    float mean = acc[col*2] * (1.0f/4096.0f);
    float var  = acc[col*2 + 1] * (1.0f/4096.0f) - mean*mean;
    float inv  = rsqrtf(var + 1e-5f);
    float sc = gamma[col] * inv;
    float sh = beta[col] - mean * sc;
    split2(vv[j]*sc + sh, hp[j], lp[j]);
  }
  size_t off = packoff(r, colb, 16);
  ((short4*)hPh)[off >> 2] = hh;
  ((short4*)hPl)[off >> 2] = ll;
}

// ---------- 9. final: inline BN2 + readout + modality softmax mix ----------
__global__ __launch_bounds__(256) void k_final2(const float* __restrict__ h, const float* __restrict__ acc2,
                                                const float* __restrict__ gamma2, const float* __restrict__ beta2,
                                                const float* __restrict__ w_ro, const float* __restrict__ cl,
                                                float* __restrict__ out) {
  int node = blockIdx.x;
  int t = threadIdx.x, m = t >> 6, lane = t & 63;
  const float* row = h + (size_t)(m*1024 + node)*512;
  float a0 = 0.f, a1 = 0.f, a2 = 0.f, a3 = 0.f;
  for (int it = 0; it < 8; ++it) {
    int k = lane + it*64;
    float mean = acc2[k*2] * (1.0f/4096.0f);
    float var  = acc2[k*2 + 1] * (1.0f/4096.0f) - mean*mean;
    float inv  = rsqrtf(var + 1e-5f);
    float sc = gamma2[k] * inv;
    float sh = beta2[k] - mean * sc;
    float hv = row[k]*sc + sh;
    float4 w = ((const float4*)w_ro)[k];
    a0 += hv*w.x; a1 += hv*w.y; a2 += hv*w.z; a3 += hv*w.w;
  }
  for (int off = 32; off > 0; off >>= 1) {
    a0 += __shfl_down(a0, off); a1 += __shfl_down(a1, off);
    a2 += __shfl_down(a2, off); a3 += __shfl_down(a3, off);
  }
  __shared__ float part[4][4];
  if (lane == 0) { part[m][0]=a0; part[m][1]=a1; part[m][2]=a2; part[m][3]=a3; }
  __syncthreads();
  if (t < 4) {
    float c0 = cl[0], c1 = cl[1], c2 = cl[2], c3 = cl[3];
    float mx = fmaxf(fmaxf(c0,c1), fmaxf(c2,c3));
    float e0 = expf(c0-mx), e1 = expf(c1-mx), e2 = expf(c2-mx), e3 = expf(c3-mx);
    float inv = 1.0f/(e0+e1+e2+e3);
    float r = (e0*part[0][t] + e1*part[1][t] + e2*part[2][t] + e3*part[3][t]) * inv;
    out[node*4 + t] = r;
  }
}

extern "C" void kernel_launch(void* const* d_in, const int* in_sizes, int n_in,
                              void* d_out, int out_size, void* d_ws, size_t ws_size,
                              hipStream_t stream) {
  const float* features = (const float*)d_in[0];
  const float* sparse   = (const float*)d_in[1];
  const float* cmix     = (const float*)d_in[2];
  const float* wAC1 = (const float*)d_in[3];
  const float* bAC1 = (const float*)d_in[4];
  const float* wCA1 = (const float*)d_in[5];
  const float* bCA1 = (const float*)d_in[6];
  const float* wAC2 = (const float*)d_in[7];
  const float* bAC2 = (const float*)d_in[8];
  const float* wCA2 = (const float*)d_in[9];
  const float* bCA2 = (const float*)d_in[10];
  const float* gamma1 = (const float*)d_in[11];
  const float* beta1  = (const float*)d_in[12];
  const float* gamma2 = (const float*)d_in[13];
  const float* beta2  = (const float*)d_in[14];
  const float* w_ro   = (const float*)d_in[15];
  float* out = (float*)d_out;

  char* ws = (char*)d_ws;
  const size_t MB = 1024ull*1024ull, KB = 1024ull;
  u64*   bits    = (u64*)(ws + 0);               // 1.25 MB
  u64*   mask    = (u64*)(ws + 2*MB);            // 2 MB (row-major)
  u64*   mask_wm = (u64*)(ws + 4*MB);            // 2 MB (word-major)
  u64*   maskT_wm= (u64*)(ws + 6*MB);            // 2 MB (word-major)
  int*   deg1    = (int*)(ws + 8*MB);            // 16 KB  [zeroed]
  float* bnacc1  = (float*)(ws + 8*MB + 16*KB);  // 4 KB   [zeroed]
  float* bnacc2  = (float*)(ws + 8*MB + 20*KB);  // 4 KB   [zeroed]
  u64*   cmask   = (u64*)(ws + 8*MB + 24*KB);    // 1 KB   [zeroed]
  int*   deg2    = (int*)(ws + 8*MB + 28*KB);    // 16 KB
  short* WT1h  = (short*)(ws + 9*MB);            // 128 KB (frag-major pack)
  short* WT1l  = (short*)(ws + 9*MB + 128*KB);   // 128 KB
  short* WT2h  = (short*)(ws + 9*MB + 256*KB);   // 512 KB
  short* WT2l  = (short*)(ws + 9*MB + 768*KB);   // 512 KB
  short* yhP   = (short*)(ws + 11*MB);           // 1 MB (dead after corr3)
  short* ymP   = (short*)(ws + 12*MB);           // 1 MB
  short* ylP   = (short*)(ws + 13*MB);           // 1 MB
  short* fPh   = (short*)(ws + 14*MB);           // 1 MB (dead after L1 dense)
  short* fPl   = (short*)(ws + 15*MB);           // 1 MB
  short* hnPh  = (short*)(ws + 16*MB);           // 4 MB (frag-major, K=512)
  short* hnPl  = (short*)(ws + 20*MB);           // 4 MB
  short* BTh   = (short*)(ws + 24*MB);           // 4 MB (frag-major, distinct from hnP!)
  short* BTl   = (short*)(ws + 28*MB);           // 4 MB
  float* Z     = (float*)(ws + 32*MB);           // 8 MB
  float* h     = (float*)(ws + 40*MB);           // 8 MB (total 48 MB)

  hipMemsetAsync(ws + 8*MB, 0, 25*KB, stream);   // deg1 + bnacc1 + bnacc2 + cmask

  // graph prep
  k_rownorm<<<dim3(4096), dim3(128), 0, stream>>>(features, yhP, ymP, ylP, fPh, fPl);
  k_corr3<<<dim3(16,16,10), dim3(256), 0, stream>>>(yhP, ymP, ylP, sparse, bits);
  k_maskrows<<<dim3(4096), dim3(64), 0, stream>>>(bits, mask, mask_wm, deg2, cmask);
  k_bittrans2<<<dim3(64,4), dim3(256), 0, stream>>>(mask, maskT_wm, deg1, cmask);
  k_prepWTall<<<dim3(8,8,2), dim3(256), 0, stream>>>(wAC1, wCA1, wAC2, wCA2, WT1h, WT1l, WT2h, WT2l);

  // layer 1:  h = relu(Z + sfac*(bits @ (nrm*Z)) + b)  [dense3 also emits BT packs]
  k_dense3<<<dim3(64,8), dim3(256), 0, stream>>>(fPh, fPl, WT1h, WT1l, Z, 4, deg1, deg2, BTh, BTl);
  k_mg4<<<dim3(32,4,2), dim3(512), 0, stream>>>(maskT_wm, mask_wm, cmask, BTh, BTl, Z,
                                                deg1, deg2, bAC1, bCA1, h, bnacc1);
  k_bnapply_split<<<dim3(2048), dim3(256), 0, stream>>>(h, bnacc1, gamma1, beta1, hnPh, hnPl);

  // layer 2
  k_dense3<<<dim3(64,8), dim3(256), 0, stream>>>(hnPh, hnPl, WT2h, WT2l, Z, 16, deg1, deg2, BTh, BTl);
  k_mg4<<<dim3(32,4,2), dim3(512), 0, stream>>>(maskT_wm, mask_wm, cmask, BTh, BTl, Z,
                                                deg1, deg2, bAC2, bCA2, h, bnacc2);

  // readout (BN2 folded inline)
  k_final2<<<dim3(1024), dim3(256), 0, stream>>>(h, bnacc2, gamma2, beta2, w_ro, cmix, out);
}

// Round 11
// 273.029 us; speedup vs baseline: 1.0847x; 1.0847x over previous
//
#include <hip/hip_runtime.h>

typedef unsigned long long u64;
typedef __attribute__((ext_vector_type(8))) short s8v;   // 8 bf16 = 4 VGPRs (MFMA A/B frag)
typedef __attribute__((ext_vector_type(4))) float f4v;   // MFMA C/D frag

__device__ __constant__ int c_pi[10]   = {0,1,2,3,0,1,2,3,3,3};
__device__ __constant__ int c_pj[10]   = {0,1,2,3,3,3,3,0,1,2};
__device__ __constant__ int c_dri[10]  = {1,5,8,10,4,7,9,4,7,9};
__device__ __constant__ int c_diag[10] = {1,1,1,1,0,0,0,0,0,0};
__device__ __constant__ int c_src[16]  = {-1,7,8,9,  4,-1,8,9,  5,5,-1,9,  6,6,6,-1};

// round-to-nearest bf16
__device__ inline unsigned short bf16rn(float v) {
  unsigned int u = __float_as_uint(v);
  unsigned int r = u + 0x7fffu + ((u >> 16) & 1u);
  return (unsigned short)(r >> 16);
}
__device__ inline void split2(float v, short& h, short& l) {
  unsigned short hs = bf16rn(v);
  float fh = __uint_as_float(((unsigned int)hs) << 16);
  h = (short)hs;
  l = (short)bf16rn(v - fh);
}
__device__ inline void split3(float v, short& h, short& m, short& l) {
  unsigned short hs = bf16rn(v);
  float fh = __uint_as_float(((unsigned int)hs) << 16);
  float r1 = v - fh;
  unsigned short ms = bf16rn(r1);
  float fm = __uint_as_float(((unsigned int)ms) << 16);
  h = (short)hs; m = (short)ms;
  l = (short)bf16rn(r1 - fm);
}

// fragment-major pack offset: row r, k-index k, KC = K/32 chunks
__device__ inline size_t packoff(int row, int k, int KC) {
  int T = row >> 4, rr = row & 15;
  int c = k >> 5, q = (k >> 3) & 3, j = k & 7;
  return (((size_t)T*KC + c)*64 + q*16 + rr)*8 + j;
}

// ---------- 1. center+normalize rows -> 3 base split packs; feature pack ----------
__global__ __launch_bounds__(128) void k_rownorm(const float* __restrict__ f,
                                                 short* __restrict__ yhP, short* __restrict__ ymP,
                                                 short* __restrict__ ylP,
                                                 short* __restrict__ fPh, short* __restrict__ fPl) {
  int r = blockIdx.x, t = threadIdx.x;
  __shared__ float red[128];
  float v = f[r*128 + t];
  red[t] = v; __syncthreads();
  for (int s = 64; s > 0; s >>= 1) { if (t < s) red[t] += red[t+s]; __syncthreads(); }
  float mean = red[0] * (1.0f/128.0f);
  __syncthreads();
  float xc = v - mean;
  red[t] = xc*xc; __syncthreads();
  for (int s = 64; s > 0; s >>= 1) { if (t < s) red[t] += red[t+s]; __syncthreads(); }
  float inv = 1.0f / sqrtf(red[0]);
  short h, m, l;
  split3(xc*inv, h, m, l);
  size_t o = packoff(r, t, 4);
  yhP[o] = h; ymP[o] = m; ylP[o] = l;
  short fh, fl; split2(v, fh, fl);
  fPh[o] = fh; fPl[o] = fl;
}

// ---------- 2. correlation bit blocks: base-pack GEMM, 6 chain combos from registers ----------
__global__ __launch_bounds__(256) void k_corr3(const short* __restrict__ yhP, const short* __restrict__ ymP,
                                               const short* __restrict__ ylP,
                                               const float* __restrict__ sparse, u64* __restrict__ bits) {
  int z = blockIdx.z;
  int bx = blockIdx.x, by = blockIdx.y;
  int dg = c_diag[z];
  if (dg && by < bx) return;
  int a0 = c_pi[z]*1024 + bx*64;
  int b0 = c_pj[z]*1024 + by*64;
  int tid = threadIdx.x, lane = tid & 63, wid = tid >> 6;
  int quad = lane >> 4, l15 = lane & 15;
  const s8v* AH = (const s8v*)yhP + ((size_t)((a0>>4) + wid))*4*64 + lane;
  const s8v* AM = (const s8v*)ymP + ((size_t)((a0>>4) + wid))*4*64 + lane;
  const s8v* AL = (const s8v*)ylP + ((size_t)((a0>>4) + wid))*4*64 + lane;
  const s8v* BH = (const s8v*)yhP + ((size_t)(b0>>4))*4*64 + lane;
  const s8v* BM = (const s8v*)ymP + ((size_t)(b0>>4))*4*64 + lane;
  const s8v* BL = (const s8v*)ylP + ((size_t)(b0>>4))*4*64 + lane;
  f4v acc[4];
  #pragma unroll
  for (int i = 0; i < 4; ++i) { acc[i][0]=0.f; acc[i][1]=0.f; acc[i][2]=0.f; acc[i][3]=0.f; }
  for (int c = 0; c < 4; ++c) {
    s8v a_h = AH[c*64];
    s8v a_m = AM[c*64];
    s8v a_l = AL[c*64];
    #pragma unroll
    for (int nt = 0; nt < 4; ++nt) {
      s8v b_h = BH[(nt*4 + c)*64];
      s8v b_m = BM[(nt*4 + c)*64];
      s8v b_l = BL[(nt*4 + c)*64];
      acc[nt] = __builtin_amdgcn_mfma_f32_16x16x32_bf16(a_h, b_h, acc[nt], 0, 0, 0);
      acc[nt] = __builtin_amdgcn_mfma_f32_16x16x32_bf16(a_m, b_m, acc[nt], 0, 0, 0);
      acc[nt] = __builtin_amdgcn_mfma_f32_16x16x32_bf16(a_h, b_m, acc[nt], 0, 0, 0);
      acc[nt] = __builtin_amdgcn_mfma_f32_16x16x32_bf16(a_m, b_h, acc[nt], 0, 0, 0);
      acc[nt] = __builtin_amdgcn_mfma_f32_16x16x32_bf16(a_h, b_l, acc[nt], 0, 0, 0);
      acc[nt] = __builtin_amdgcn_mfma_f32_16x16x32_bf16(a_l, b_h, acc[nt], 0, 0, 0);
    }
  }
  __shared__ unsigned char lby[64*68];
  float sv = sparse[c_dri[z]];
  float dr = 1.0f / (1.0f + expf(-sv));
  #pragma unroll
  for (int nt = 0; nt < 4; ++nt) {
    #pragma unroll
    for (int reg = 0; reg < 4; ++reg) {
      int lr = wid*16 + quad*4 + reg;
      int lc = nt*16 + l15;
      int ga = bx*64 + lr, gb = by*64 + lc;
      int on = (fabsf(acc[nt][reg]) > dr) && !(dg && (ga == gb));
      lby[lr*68 + lc] = (unsigned char)on;
    }
  }
  __syncthreads();
  if (tid < 64) {
    u64 w = 0;
    for (int c2 = 0; c2 < 64; ++c2) w |= ((u64)lby[tid*68 + c2]) << c2;
    bits[z*16384 + (bx*64 + tid)*16 + by] = w;
    if (dg && bx != by) {
      u64 wt = 0;
      for (int c2 = 0; c2 < 64; ++c2) wt |= ((u64)lby[c2*68 + tid]) << c2;
      bits[z*16384 + (by*64 + tid)*16 + bx] = wt;
    }
  }
}

// ---------- 3. mask rows: 8-deep pipelined bit-walk ----------
__global__ __launch_bounds__(64) void k_maskrows(const u64* __restrict__ bits, u64* __restrict__ mask,
                                                 u64* __restrict__ mask_wm, int* __restrict__ deg2,
                                                 u64* __restrict__ cmask) {
  int u = blockIdx.x;
  int i = u >> 10, a = u & 1023;
  int t = threadIdx.x;
  __shared__ u64 drow[16];
  if (t < 16) drow[t] = bits[i*16384 + a*16 + t];
  __syncthreads();
  int j = t >> 4, wl = t & 15;
  u64 out;
  if (j == i) {
    out = drow[wl];
  } else {
    const u64* S = bits + c_src[i*4 + j]*16384;
    out = 0;
    for (int w2 = 0; w2 < 16; ++w2) {
      u64 m = drow[w2];
      const u64* base = S + (size_t)w2*1024 + wl;
      while (m) {
        u64 v0 = 0, v1 = 0, v2 = 0, v3 = 0, v4 = 0, v5 = 0, v6 = 0, v7 = 0;
        int b = __builtin_ctzll(m); m &= m - 1; v0 = base[b*16];
        if (m) { b = __builtin_ctzll(m); m &= m - 1; v1 = base[b*16]; }
        if (m) { b = __builtin_ctzll(m); m &= m - 1; v2 = base[b*16]; }
        if (m) { b = __builtin_ctzll(m); m &= m - 1; v3 = base[b*16]; }
        if (m) { b = __builtin_ctzll(m); m &= m - 1; v4 = base[b*16]; }
        if (m) { b = __builtin_ctzll(m); m &= m - 1; v5 = base[b*16]; }
        if (m) { b = __builtin_ctzll(m); m &= m - 1; v6 = base[b*16]; }
        if (m) { b = __builtin_ctzll(m); m &= m - 1; v7 = base[b*16]; }
        out |= ((v0 | v1) | (v2 | v3)) | ((v4 | v5) | (v6 | v7));
      }
    }
  }
  mask[(size_t)u*64 + t] = out;
  mask_wm[(size_t)t*4096 + u] = out;
  u64 bal = __ballot(out != 0ULL);
  if (t == 0 && bal) atomicOr((unsigned long long*)&cmask[64 + (u >> 6)], bal);
  int cnt = __popcll(out);
  for (int off = 32; off > 0; off >>= 1) cnt += __shfl_down(cnt, off);
  if (t == 0) deg2[u] = cnt;
}

// ---------- 4. bit transpose -> maskT word-major + deg1 atomics + cmask[g=0] ----------
__global__ __launch_bounds__(256) void k_bittrans2(const u64* __restrict__ mask, u64* __restrict__ wmT,
                                                   int* __restrict__ deg1, u64* __restrict__ cmask) {
  __shared__ u64 tile[4096];   // 64 rows x 64 words = 32 KB
  int tI = blockIdx.x, tid = threadIdx.x;
  for (int e = tid; e < 4096; e += 256) tile[e] = mask[(size_t)tI*4096 + e];
  __syncthreads();
  int wv = tid >> 6, lane = tid & 63;
  int tJ0 = blockIdx.y*16;
  for (int j = 0; j < 4; ++j) {
    int tJ = tJ0 + wv*4 + j;
    u64 o = 0;
    #pragma unroll 8
    for (int k = 0; k < 64; ++k) o |= ((tile[k*64 + tJ] >> lane) & 1ULL) << k;
    wmT[(size_t)tI*4096 + tJ*64 + lane] = o;
    atomicAdd(&deg1[tJ*64 + lane], __popcll(o));
    u64 bal = __ballot(o != 0ULL);
    if (lane == 0 && bal) atomicOr((unsigned long long*)&cmask[tJ], 1ULL << tI);
  }
}

// ---------- 5. weight prep (both layers in one dispatch) ----------
__global__ __launch_bounds__(256) void k_prepWTall(const float* __restrict__ wAC1, const float* __restrict__ wCA1,
                                                   const float* __restrict__ wAC2, const float* __restrict__ wCA2,
                                                   short* __restrict__ w1h, short* __restrict__ w1l,
                                                   short* __restrict__ w2h, short* __restrict__ w2l) {
  __shared__ float lds[64*65];
  int z = blockIdx.z;
  int bx = blockIdx.x;
  if (z == 0 && bx >= 2) return;
  int K = z ? 512 : 128;
  const float* Wa = z ? wAC2 : wAC1;
  const float* Wb = z ? wCA2 : wCA1;
  short* wph = z ? w2h : w1h;
  short* wpl = z ? w2l : w1l;
  int tid = threadIdx.x;
  int k0 = bx*64, n0 = blockIdx.y*64;
  const float* W = (n0 < 256) ? Wa : Wb;
  int nc0 = n0 & 255;
  for (int e = tid; e < 4096; e += 256) {
    int r = e >> 6, c = e & 63;
    lds[r*65 + c] = W[(size_t)(k0+r)*256 + nc0 + c];
  }
  __syncthreads();
  int KC = K >> 5;
  for (int e = tid; e < 4096; e += 256) {
    int j = e & 7, ln = (e >> 3) & 63, cp = (e >> 9) & 1, Tp = e >> 10;
    int q = ln >> 4, rr = ln & 15;
    float v = lds[(cp*32 + q*8 + j)*65 + (Tp*16 + rr)];
    short h, l; split2(v, h, l);
    size_t off = (((size_t)((n0>>4)+Tp)*KC + (k0>>5)+cp)*64 + ln)*8 + j;
    wph[off] = h; wpl[off] = l;
  }
}

// ---------- 6. dense GEMM + fused B-prep: Z tile + nrm-scaled frag-major BT packs ----------
__global__ __launch_bounds__(256) void k_dense3(const short* __restrict__ Ah, const short* __restrict__ Al,
                                                const short* __restrict__ Bh, const short* __restrict__ Bl,
                                                float* __restrict__ Z, int KC,
                                                const int* __restrict__ deg1, const int* __restrict__ deg2,
                                                short* __restrict__ bph, short* __restrict__ bpl) {
  __shared__ float tile[64*65];
  int tid = threadIdx.x, lane = tid & 63, wid = tid >> 6;
  int quad = lane >> 4, l15 = lane & 15;
  int m0 = blockIdx.x*64, n0 = blockIdx.y*64;
  const s8v* ah = (const s8v*)Ah + ((size_t)((m0>>4) + wid))*KC*64 + lane;
  const s8v* al = (const s8v*)Al + ((size_t)((m0>>4) + wid))*KC*64 + lane;
  const s8v* bh0 = (const s8v*)Bh + ((size_t)((n0>>4) + 0))*KC*64 + lane;
  const s8v* bh1 = (const s8v*)Bh + ((size_t)((n0>>4) + 1))*KC*64 + lane;
  const s8v* bh2 = (const s8v*)Bh + ((size_t)((n0>>4) + 2))*KC*64 + lane;
  const s8v* bh3 = (const s8v*)Bh + ((size_t)((n0>>4) + 3))*KC*64 + lane;
  const s8v* bl0 = (const s8v*)Bl + ((size_t)((n0>>4) + 0))*KC*64 + lane;
  const s8v* bl1 = (const s8v*)Bl + ((size_t)((n0>>4) + 1))*KC*64 + lane;
  const s8v* bl2 = (const s8v*)Bl + ((size_t)((n0>>4) + 2))*KC*64 + lane;
  const s8v* bl3 = (const s8v*)Bl + ((size_t)((n0>>4) + 3))*KC*64 + lane;
  f4v acc[4];
  #pragma unroll
  for (int i = 0; i < 4; ++i) { acc[i][0]=0.f; acc[i][1]=0.f; acc[i][2]=0.f; acc[i][3]=0.f; }
  for (int c = 0; c < KC; ++c) {
    s8v a_h = ah[c*64];
    s8v a_l = al[c*64];
    acc[0] = __builtin_amdgcn_mfma_f32_16x16x32_bf16(a_h, bh0[c*64], acc[0], 0, 0, 0);
    acc[0] = __builtin_amdgcn_mfma_f32_16x16x32_bf16(a_h, bl0[c*64], acc[0], 0, 0, 0);
    acc[0] = __builtin_amdgcn_mfma_f32_16x16x32_bf16(a_l, bh0[c*64], acc[0], 0, 0, 0);
    acc[1] = __builtin_amdgcn_mfma_f32_16x16x32_bf16(a_h, bh1[c*64], acc[1], 0, 0, 0);
    acc[1] = __builtin_amdgcn_mfma_f32_16x16x32_bf16(a_h, bl1[c*64], acc[1], 0, 0, 0);
    acc[1] = __builtin_amdgcn_mfma_f32_16x16x32_bf16(a_l, bh1[c*64], acc[1], 0, 0, 0);
    acc[2] = __builtin_amdgcn_mfma_f32_16x16x32_bf16(a_h, bh2[c*64], acc[2], 0, 0, 0);
    acc[2] = __builtin_amdgcn_mfma_f32_16x16x32_bf16(a_h, bl2[c*64], acc[2], 0, 0, 0);
    acc[2] = __builtin_amdgcn_mfma_f32_16x16x32_bf16(a_l, bh2[c*64], acc[2], 0, 0, 0);
    acc[3] = __builtin_amdgcn_mfma_f32_16x16x32_bf16(a_h, bh3[c*64], acc[3], 0, 0, 0);
    acc[3] = __builtin_amdgcn_mfma_f32_16x16x32_bf16(a_h, bl3[c*64], acc[3], 0, 0, 0);
    acc[3] = __builtin_amdgcn_mfma_f32_16x16x32_bf16(a_l, bh3[c*64], acc[3], 0, 0, 0);
  }
  #pragma unroll
  for (int nt = 0; nt < 4; ++nt) {
    #pragma unroll
    for (int reg = 0; reg < 4; ++reg) {
      int rl = wid*16 + quad*4 + reg;
      int cl = nt*16 + l15;
      float v = acc[nt][reg];
      Z[(size_t)(m0+rl)*512 + n0 + cl] = v;
      tile[rl*65 + cl] = v;
    }
  }
  __syncthreads();
  const int* dg = (n0 < 256) ? deg1 : deg2;
  for (int e = tid; e < 4096; e += 256) {   // pack-major write order (coalesced)
    int j = e & 7, ln = (e >> 3) & 63, cp = (e >> 9) & 1, Tp = e >> 10;
    int q = ln >> 4, rr = ln & 15;
    int krow = cp*32 + q*8 + j;             // node-local row
    int d = dg[m0 + krow];
    float nr = d > 0 ? (1.0f / sqrtf((float)d)) : 0.0f;
    float v = tile[krow*65 + (Tp*16 + rr)] * nr;
    short h, l; split2(v, h, l);
    size_t off = (((size_t)((n0>>4)+Tp)*128 + (m0>>5)+cp)*64 + ln)*8 + j;
    bph[off] = h; bpl[off] = l;
  }
}

// ---------- 7. mask GEMM v5: 4-way K-split, 16 waves/block (full occupancy) + fused BN sums ----------
__global__ __launch_bounds__(1024) void k_mg5(const u64* __restrict__ wmT, const u64* __restrict__ wmR,
                                              const u64* __restrict__ cmask,
                                              const short* __restrict__ bph, const short* __restrict__ bpl,
                                              const float* __restrict__ Z,
                                              const int* __restrict__ deg1, const int* __restrict__ deg2,
                                              const float* __restrict__ biasA, const float* __restrict__ biasB,
                                              float* __restrict__ h, float* __restrict__ bnacc) {
  __shared__ s8v lut[256];          // byte -> 8 bf16 {0,1}   (4 KB)
  __shared__ float tile[3*64*65];   // K-quarter partials for ks=1,2,3   (~50 KB)
  int tid = threadIdx.x;
  if (tid < 256) {
    s8v e;
    #pragma unroll
    for (int j = 0; j < 8; ++j) e[j] = ((tid >> j) & 1) ? (short)0x3F80 : (short)0;
    lut[tid] = e;
  }
  __syncthreads();
  int g = blockIdx.z;
  const u64* wm = g ? wmR : wmT;
  u64 cm = cmask[g*64 + blockIdx.x];
  int m0 = blockIdx.x*64, n0 = blockIdx.y*64;
  int lane = tid & 63, wid = tid >> 6, quad = lane >> 4, l15 = lane & 15;
  int nw = wid & 3, ks = wid >> 2;               // ks in 0..3: K-quarter
  u64 cmw = (cm >> (ks*16)) & 0xffffULL;
  int kwb = ks << 4;
  int T = g*16 + (n0 >> 4) + nw;
  const s8v* BH = (const s8v*)bph + (size_t)T*128*64 + lane;
  const s8v* BL = (const s8v*)bpl + (size_t)T*128*64 + lane;
  f4v acc[4];
  #pragma unroll
  for (int i = 0; i < 4; ++i) { acc[i][0]=0.f; acc[i][1]=0.f; acc[i][2]=0.f; acc[i][3]=0.f; }
  s8v z8;
  #pragma unroll
  for (int j = 0; j < 8; ++j) z8[j] = 0;

  int kw = -1;
  u64 w0 = 0, w1 = 0, w2 = 0, w3 = 0;
  s8v b0h = z8, b0l = z8, b1h = z8, b1l = z8;
  if (cmw) {
    kw = kwb + __builtin_ctzll(cmw); cmw &= cmw - 1;
    const u64* wp = wm + (size_t)kw*4096 + m0;
    w0 = wp[l15]; w1 = wp[16 + l15]; w2 = wp[32 + l15]; w3 = wp[48 + l15];
    b0h = BH[(kw*2)*64];   b0l = BL[(kw*2)*64];
    b1h = BH[(kw*2+1)*64]; b1l = BL[(kw*2+1)*64];
  }
  while (kw >= 0) {
    int kwn = -1;
    u64 nw0 = 0, nw1 = 0, nw2 = 0, nw3 = 0;
    s8v nb0h = z8, nb0l = z8, nb1h = z8, nb1l = z8;
    if (cmw) {                                  // prefetch next chunk (mask words + B frags)
      kwn = kwb + __builtin_ctzll(cmw); cmw &= cmw - 1;
      const u64* wp = wm + (size_t)kwn*4096 + m0;
      nw0 = wp[l15]; nw1 = wp[16 + l15]; nw2 = wp[32 + l15]; nw3 = wp[48 + l15];
      nb0h = BH[(kwn*2)*64];   nb0l = BL[(kwn*2)*64];
      nb1h = BH[(kwn*2+1)*64]; nb1l = BL[(kwn*2+1)*64];
    }
    {
      unsigned sh = quad*8;
      s8v a0 = lut[(unsigned)(w0 >> sh) & 0xffu];
      s8v a1 = lut[(unsigned)(w1 >> sh) & 0xffu];
      s8v a2 = lut[(unsigned)(w2 >> sh) & 0xffu];
      s8v a3 = lut[(unsigned)(w3 >> sh) & 0xffu];
      acc[0] = __builtin_amdgcn_mfma_f32_16x16x32_bf16(a0, b0h, acc[0], 0, 0, 0);
      acc[0] = __builtin_amdgcn_mfma_f32_16x16x32_bf16(a0, b0l, acc[0], 0, 0, 0);
      acc[1] = __builtin_amdgcn_mfma_f32_16x16x32_bf16(a1, b0h, acc[1], 0, 0, 0);
      acc[1] = __builtin_amdgcn_mfma_f32_16x16x32_bf16(a1, b0l, acc[1], 0, 0, 0);
      acc[2] = __builtin_amdgcn_mfma_f32_16x16x32_bf16(a2, b0h, acc[2], 0, 0, 0);
      acc[2] = __builtin_amdgcn_mfma_f32_16x16x32_bf16(a2, b0l, acc[2], 0, 0, 0);
      acc[3] = __builtin_amdgcn_mfma_f32_16x16x32_bf16(a3, b0h, acc[3], 0, 0, 0);
      acc[3] = __builtin_amdgcn_mfma_f32_16x16x32_bf16(a3, b0l, acc[3], 0, 0, 0);
      sh = 32 + quad*8;
      a0 = lut[(unsigned)(w0 >> sh) & 0xffu];
      a1 = lut[(unsigned)(w1 >> sh) & 0xffu];
      a2 = lut[(unsigned)(w2 >> sh) & 0xffu];
      a3 = lut[(unsigned)(w3 >> sh) & 0xffu];
      acc[0] = __builtin_amdgcn_mfma_f32_16x16x32_bf16(a0, b1h, acc[0], 0, 0, 0);
      acc[0] = __builtin_amdgcn_mfma_f32_16x16x32_bf16(a0, b1l, acc[0], 0, 0, 0);
      acc[1] = __builtin_amdgcn_mfma_f32_16x16x32_bf16(a1, b1h, acc[1], 0, 0, 0);
      acc[1] = __builtin_amdgcn_mfma_f32_16x16x32_bf16(a1, b1l, acc[1], 0, 0, 0);
      acc[2] = __builtin_amdgcn_mfma_f32_16x16x32_bf16(a2, b1h, acc[2], 0, 0, 0);
      acc[2] = __builtin_amdgcn_mfma_f32_16x16x32_bf16(a2, b1l, acc[2], 0, 0, 0);
      acc[3] = __builtin_amdgcn_mfma_f32_16x16x32_bf16(a3, b1h, acc[3], 0, 0, 0);
      acc[3] = __builtin_amdgcn_mfma_f32_16x16x32_bf16(a3, b1l, acc[3], 0, 0, 0);
    }
    kw = kwn;
    w0 = nw0; w1 = nw1; w2 = nw2; w3 = nw3;
    b0h = nb0h; b0l = nb0l; b1h = nb1h; b1l = nb1l;
  }
  // combine K-quarters through LDS; epilogue + BN partial sums by ks==0 waves
  int nl = nw*16 + l15;
  if (ks > 0) {
    float* tp = tile + (ks-1)*64*65;
    #pragma unroll
    for (int mf = 0; mf < 4; ++mf) {
      #pragma unroll
      for (int reg = 0; reg < 4; ++reg)
        tp[(mf*16 + quad*4 + reg)*65 + nl] = acc[mf][reg];
    }
  }
  __syncthreads();
  if (ks == 0) {
    int n = n0 + nl;
    const int* dgp = g ? deg2 : deg1;
    float bn = (g ? biasB : biasA)[n];
    int zoff = g*256;
    float sv = 0.0f, qv = 0.0f;
    #pragma unroll
    for (int mf = 0; mf < 4; ++mf) {
      #pragma unroll
      for (int reg = 0; reg < 4; ++reg) {
        int v = m0 + mf*16 + quad*4 + reg;
        int to = (mf*16 + quad*4 + reg)*65 + nl;
        float s = acc[mf][reg] + (tile[to] + tile[64*65 + to]) + tile[2*64*65 + to];
        int d = dgp[v];
        float sfac = 0.0f;
        if (d > 0) { float df = (float)d; sfac = (1.0f / sqrtf(df)) / df; }
        float val = Z[(size_t)v*512 + zoff + n] + sfac*s + bn;
        val = fmaxf(val, 0.0f);
        h[(size_t)v*512 + zoff + n] = val;
        sv += val; qv += val*val;
      }
    }
    // reduce over the 4 quads sharing column n
    sv += __shfl_down(sv, 32); qv += __shfl_down(qv, 32);
    sv += __shfl_down(sv, 16); qv += __shfl_down(qv, 16);
    if (quad == 0) {
      int col = zoff + n;
      atomicAdd(&bnacc[col*2 + 0], sv);
      atomicAdd(&bnacc[col*2 + 1], qv);
    }
  }
}

// ---------- 8. BN apply + split to frag-major hn packs (K=512) ----------
__global__ __launch_bounds__(256) void k_bnapply_split(const float* __restrict__ h, const float* __restrict__ acc,
                                                       const float* __restrict__ gamma, const float* __restrict__ beta,
                                                       short* __restrict__ hPh, short* __restrict__ hPl) {
  int i = blockIdx.x*256 + threadIdx.x;       // 524288 float4s
  float4 v = ((const float4*)h)[i];
  int r = i >> 7;
  int colb = (i & 127) * 4;
  float vv[4] = {v.x, v.y, v.z, v.w};
  short4 hh, ll;
  short* hp = (short*)&hh; short* lp = (short*)&ll;
  #pragma unroll
  for (int j = 0; j < 4; ++j) {
    int col = colb + j;
    float mean = acc[col*2] * (1.0f/4096.0f);
    float var  = acc[col*2 + 1] * (1.0f/4096.0f) - mean*mean;
    float inv  = rsqrtf(var + 1e-5f);
    float sc = gamma[col] * inv;
    float sh = beta[col] - mean * sc;
    split2(vv[j]*sc + sh, hp[j], lp[j]);
  }
  size_t off = packoff(r, colb, 16);
  ((short4*)hPh)[off >> 2] = hh;
  ((short4*)hPl)[off >> 2] = ll;
}

// ---------- 9. final: inline BN2 + readout + modality softmax mix ----------
__global__ __launch_bounds__(256) void k_final2(const float* __restrict__ h, const float* __restrict__ acc2,
                                                const float* __restrict__ gamma2, const float* __restrict__ beta2,
                                                const float* __restrict__ w_ro, const float* __restrict__ cl,
                                                float* __restrict__ out) {
  int node = blockIdx.x;
  int t = threadIdx.x, m = t >> 6, lane = t & 63;
  const float* row = h + (size_t)(m*1024 + node)*512;
  float a0 = 0.f, a1 = 0.f, a2 = 0.f, a3 = 0.f;
  for (int it = 0; it < 8; ++it) {
    int k = lane + it*64;
    float mean = acc2[k*2] * (1.0f/4096.0f);
    float var  = acc2[k*2 + 1] * (1.0f/4096.0f) - mean*mean;
    float inv  = rsqrtf(var + 1e-5f);
    float sc = gamma2[k] * inv;
    float sh = beta2[k] - mean * sc;
    float hv = row[k]*sc + sh;
    float4 w = ((const float4*)w_ro)[k];
    a0 += hv*w.x; a1 += hv*w.y; a2 += hv*w.z; a3 += hv*w.w;
  }
  for (int off = 32; off > 0; off >>= 1) {
    a0 += __shfl_down(a0, off); a1 += __shfl_down(a1, off);
    a2 += __shfl_down(a2, off); a3 += __shfl_down(a3, off);
  }
  __shared__ float part[4][4];
  if (lane == 0) { part[m][0]=a0; part[m][1]=a1; part[m][2]=a2; part[m][3]=a3; }
  __syncthreads();
  if (t < 4) {
    float c0 = cl[0], c1 = cl[1], c2 = cl[2], c3 = cl[3];
    float mx = fmaxf(fmaxf(c0,c1), fmaxf(c2,c3));
    float e0 = expf(c0-mx), e1 = expf(c1-mx), e2 = expf(c2-mx), e3 = expf(c3-mx);
    float inv = 1.0f/(e0+e1+e2+e3);
    float r = (e0*part[0][t] + e1*part[1][t] + e2*part[2][t] + e3*part[3][t]) * inv;
    out[node*4 + t] = r;
  }
}

extern "C" void kernel_launch(void* const* d_in, const int* in_sizes, int n_in,
                              void* d_out, int out_size, void* d_ws, size_t ws_size,
                              hipStream_t stream) {
  const float* features = (const float*)d_in[0];
  const float* sparse   = (const float*)d_in[1];
  const float* cmix     = (const float*)d_in[2];
  const float* wAC1 = (const float*)d_in[3];
  const float* bAC1 = (const float*)d_in[4];
  const float* wCA1 = (const float*)d_in[5];
  const float* bCA1 = (const float*)d_in[6];
  const float* wAC2 = (const float*)d_in[7];
  const float* bAC2 = (const float*)d_in[8];
  const float* wCA2 = (const float*)d_in[9];
  const float* bCA2 = (const float*)d_in[10];
  const float* gamma1 = (const float*)d_in[11];
  const float* beta1  = (const float*)d_in[12];
  const float* gamma2 = (const float*)d_in[13];
  const float* beta2  = (const float*)d_in[14];
  const float* w_ro   = (const float*)d_in[15];
  float* out = (float*)d_out;

  char* ws = (char*)d_ws;
  const size_t MB = 1024ull*1024ull, KB = 1024ull;
  u64*   bits    = (u64*)(ws + 0);               // 1.25 MB
  u64*   mask    = (u64*)(ws + 2*MB);            // 2 MB (row-major)
  u64*   mask_wm = (u64*)(ws + 4*MB);            // 2 MB (word-major)
  u64*   maskT_wm= (u64*)(ws + 6*MB);            // 2 MB (word-major)
  int*   deg1    = (int*)(ws + 8*MB);            // 16 KB  [zeroed]
  float* bnacc1  = (float*)(ws + 8*MB + 16*KB);  // 4 KB   [zeroed]
  float* bnacc2  = (float*)(ws + 8*MB + 20*KB);  // 4 KB   [zeroed]
  u64*   cmask   = (u64*)(ws + 8*MB + 24*KB);    // 1 KB   [zeroed]
  int*   deg2    = (int*)(ws + 8*MB + 28*KB);    // 16 KB
  short* WT1h  = (short*)(ws + 9*MB);            // 128 KB (frag-major pack)
  short* WT1l  = (short*)(ws + 9*MB + 128*KB);   // 128 KB
  short* WT2h  = (short*)(ws + 9*MB + 256*KB);   // 512 KB
  short* WT2l  = (short*)(ws + 9*MB + 768*KB);   // 512 KB
  short* yhP   = (short*)(ws + 11*MB);           // 1 MB (dead after corr3)
  short* ymP   = (short*)(ws + 12*MB);           // 1 MB
  short* ylP   = (short*)(ws + 13*MB);           // 1 MB
  short* fPh   = (short*)(ws + 14*MB);           // 1 MB (dead after L1 dense)
  short* fPl   = (short*)(ws + 15*MB);           // 1 MB
  short* hnPh  = (short*)(ws + 16*MB);           // 4 MB (frag-major, K=512)
  short* hnPl  = (short*)(ws + 20*MB);           // 4 MB
  short* BTh   = (short*)(ws + 24*MB);           // 4 MB (frag-major, distinct from hnP!)
  short* BTl   = (short*)(ws + 28*MB);           // 4 MB
  float* Z     = (float*)(ws + 32*MB);           // 8 MB
  float* h     = (float*)(ws + 40*MB);           // 8 MB (total 48 MB)

  hipMemsetAsync(ws + 8*MB, 0, 25*KB, stream);   // deg1 + bnacc1 + bnacc2 + cmask

  // graph prep
  k_rownorm<<<dim3(4096), dim3(128), 0, stream>>>(features, yhP, ymP, ylP, fPh, fPl);
  k_corr3<<<dim3(16,16,10), dim3(256), 0, stream>>>(yhP, ymP, ylP, sparse, bits);
  k_maskrows<<<dim3(4096), dim3(64), 0, stream>>>(bits, mask, mask_wm, deg2, cmask);
  k_bittrans2<<<dim3(64,4), dim3(256), 0, stream>>>(mask, maskT_wm, deg1, cmask);
  k_prepWTall<<<dim3(8,8,2), dim3(256), 0, stream>>>(wAC1, wCA1, wAC2, wCA2, WT1h, WT1l, WT2h, WT2l);

  // layer 1:  h = relu(Z + sfac*(bits @ (nrm*Z)) + b)  [dense3 also emits BT packs]
  k_dense3<<<dim3(64,8), dim3(256), 0, stream>>>(fPh, fPl, WT1h, WT1l, Z, 4, deg1, deg2, BTh, BTl);
  k_mg5<<<dim3(64,4,2), dim3(1024), 0, stream>>>(maskT_wm, mask_wm, cmask, BTh, BTl, Z,
                                                 deg1, deg2, bAC1, bCA1, h, bnacc1);
  k_bnapply_split<<<dim3(2048), dim3(256), 0, stream>>>(h, bnacc1, gamma1, beta1, hnPh, hnPl);

  // layer 2
  k_dense3<<<dim3(64,8), dim3(256), 0, stream>>>(hnPh, hnPl, WT2h, WT2l, Z, 16, deg1, deg2, BTh, BTl);
  k_mg5<<<dim3(64,4,2), dim3(1024), 0, stream>>>(maskT_wm, mask_wm, cmask, BTh, BTl, Z,
                                                 deg1, deg2, bAC2, bCA2, h, bnacc2);

  // readout (BN2 folded inline)
  k_final2<<<dim3(1024), dim3(256), 0, stream>>>(h, bnacc2, gamma2, beta2, w_ro, cmix, out);
}

// Round 12
// 261.585 us; speedup vs baseline: 1.1321x; 1.0437x over previous
//
#include <hip/hip_runtime.h>

typedef unsigned long long u64;
typedef __attribute__((ext_vector_type(8))) short s8v;   // 8 bf16 = 4 VGPRs (MFMA A/B frag)
typedef __attribute__((ext_vector_type(4))) float f4v;   // MFMA C/D frag

__device__ __constant__ int c_pi[10]   = {0,1,2,3,0,1,2,3,3,3};
__device__ __constant__ int c_pj[10]   = {0,1,2,3,3,3,3,0,1,2};
__device__ __constant__ int c_dri[10]  = {1,5,8,10,4,7,9,4,7,9};
__device__ __constant__ int c_diag[10] = {1,1,1,1,0,0,0,0,0,0};
__device__ __constant__ int c_src[16]  = {-1,7,8,9,  4,-1,8,9,  5,5,-1,9,  6,6,6,-1};

// round-to-nearest bf16
__device__ inline unsigned short bf16rn(float v) {
  unsigned int u = __float_as_uint(v);
  unsigned int r = u + 0x7fffu + ((u >> 16) & 1u);
  return (unsigned short)(r >> 16);
}
__device__ inline void split2(float v, short& h, short& l) {
  unsigned short hs = bf16rn(v);
  float fh = __uint_as_float(((unsigned int)hs) << 16);
  h = (short)hs;
  l = (short)bf16rn(v - fh);
}
__device__ inline void split3(float v, short& h, short& m, short& l) {
  unsigned short hs = bf16rn(v);
  float fh = __uint_as_float(((unsigned int)hs) << 16);
  float r1 = v - fh;
  unsigned short ms = bf16rn(r1);
  float fm = __uint_as_float(((unsigned int)ms) << 16);
  h = (short)hs; m = (short)ms;
  l = (short)bf16rn(r1 - fm);
}

// fragment-major pack offset: row r, k-index k, KC = K/32 chunks
__device__ inline size_t packoff(int row, int k, int KC) {
  int T = row >> 4, rr = row & 15;
  int c = k >> 5, q = (k >> 3) & 3, j = k & 7;
  return (((size_t)T*KC + c)*64 + q*16 + rr)*8 + j;
}

// ---------- 1. center+normalize rows -> 3 base split packs; feature pack; fused ws-zeroing ----------
__global__ __launch_bounds__(128) void k_rownorm(const float* __restrict__ f,
                                                 short* __restrict__ yhP, short* __restrict__ ymP,
                                                 short* __restrict__ ylP,
                                                 short* __restrict__ fPh, short* __restrict__ fPl,
                                                 int* __restrict__ zbase) {
  int r = blockIdx.x, t = threadIdx.x;
  int gid = r*128 + t;
  if (gid < 6400) zbase[gid] = 0;        // deg1(4096) + bnacc1(1024) + bnacc2(1024) + cmask(256)
  __shared__ float red[128];
  float v = f[r*128 + t];
  red[t] = v; __syncthreads();
  for (int s = 64; s > 0; s >>= 1) { if (t < s) red[t] += red[t+s]; __syncthreads(); }
  float mean = red[0] * (1.0f/128.0f);
  __syncthreads();
  float xc = v - mean;
  red[t] = xc*xc; __syncthreads();
  for (int s = 64; s > 0; s >>= 1) { if (t < s) red[t] += red[t+s]; __syncthreads(); }
  float inv = 1.0f / sqrtf(red[0]);
  short h, m, l;
  split3(xc*inv, h, m, l);
  size_t o = packoff(r, t, 4);
  yhP[o] = h; ymP[o] = m; ylP[o] = l;
  short fh, fl; split2(v, fh, fl);
  fPh[o] = fh; fPl[o] = fl;
}

// ---------- 2. correlation bit blocks (z<10) + weight prep (z=10,11) ----------
__global__ __launch_bounds__(256) void k_corr3(const short* __restrict__ yhP, const short* __restrict__ ymP,
                                               const short* __restrict__ ylP,
                                               const float* __restrict__ sparse, u64* __restrict__ bits,
                                               const float* __restrict__ wAC1, const float* __restrict__ wCA1,
                                               const float* __restrict__ wAC2, const float* __restrict__ wCA2,
                                               short* __restrict__ w1h, short* __restrict__ w1l,
                                               short* __restrict__ w2h, short* __restrict__ w2l) {
  __shared__ char smem[64*65*4];   // 16.6 KB: float lds (prepWT) or uchar lby (corr)
  int z = blockIdx.z;
  int bx = blockIdx.x, by = blockIdx.y;
  int tid = threadIdx.x;
  if (z >= 10) {                   // fused weight prep
    int zz = z - 10;               // 0: layer2 (K=512), 1: layer1 (K=128)
    int K = zz ? 128 : 512;
    if (by >= 8 || bx >= (K >> 6)) return;
    const float* Wa = zz ? wAC1 : wAC2;
    const float* Wb = zz ? wCA1 : wCA2;
    short* wph = zz ? w1h : w2h;
    short* wpl = zz ? w1l : w2l;
    float* lds = (float*)smem;
    int k0 = bx*64, n0 = by*64;
    const float* W = (n0 < 256) ? Wa : Wb;
    int nc0 = n0 & 255;
    for (int e = tid; e < 4096; e += 256) {
      int r = e >> 6, c = e & 63;
      lds[r*65 + c] = W[(size_t)(k0+r)*256 + nc0 + c];
    }
    __syncthreads();
    int KC = K >> 5;
    for (int e = tid; e < 4096; e += 256) {
      int j = e & 7, ln = (e >> 3) & 63, cp = (e >> 9) & 1, Tp = e >> 10;
      int q = ln >> 4, rr = ln & 15;
      float v = lds[(cp*32 + q*8 + j)*65 + (Tp*16 + rr)];
      short h, l; split2(v, h, l);
      size_t off = (((size_t)((n0>>4)+Tp)*KC + (k0>>5)+cp)*64 + ln)*8 + j;
      wph[off] = h; wpl[off] = l;
    }
    return;
  }
  int dg = c_diag[z];
  if (dg && by < bx) return;
  int a0 = c_pi[z]*1024 + bx*64;
  int b0 = c_pj[z]*1024 + by*64;
  int lane = tid & 63, wid = tid >> 6;
  int quad = lane >> 4, l15 = lane & 15;
  const s8v* AH = (const s8v*)yhP + ((size_t)((a0>>4) + wid))*4*64 + lane;
  const s8v* AM = (const s8v*)ymP + ((size_t)((a0>>4) + wid))*4*64 + lane;
  const s8v* AL = (const s8v*)ylP + ((size_t)((a0>>4) + wid))*4*64 + lane;
  const s8v* BH = (const s8v*)yhP + ((size_t)(b0>>4))*4*64 + lane;
  const s8v* BM = (const s8v*)ymP + ((size_t)(b0>>4))*4*64 + lane;
  const s8v* BL = (const s8v*)ylP + ((size_t)(b0>>4))*4*64 + lane;
  f4v acc[4];
  #pragma unroll
  for (int i = 0; i < 4; ++i) { acc[i][0]=0.f; acc[i][1]=0.f; acc[i][2]=0.f; acc[i][3]=0.f; }
  for (int c = 0; c < 4; ++c) {
    s8v a_h = AH[c*64];
    s8v a_m = AM[c*64];
    s8v a_l = AL[c*64];
    #pragma unroll
    for (int nt = 0; nt < 4; ++nt) {
      s8v b_h = BH[(nt*4 + c)*64];
      s8v b_m = BM[(nt*4 + c)*64];
      s8v b_l = BL[(nt*4 + c)*64];
      acc[nt] = __builtin_amdgcn_mfma_f32_16x16x32_bf16(a_h, b_h, acc[nt], 0, 0, 0);
      acc[nt] = __builtin_amdgcn_mfma_f32_16x16x32_bf16(a_m, b_m, acc[nt], 0, 0, 0);
      acc[nt] = __builtin_amdgcn_mfma_f32_16x16x32_bf16(a_h, b_m, acc[nt], 0, 0, 0);
      acc[nt] = __builtin_amdgcn_mfma_f32_16x16x32_bf16(a_m, b_h, acc[nt], 0, 0, 0);
      acc[nt] = __builtin_amdgcn_mfma_f32_16x16x32_bf16(a_h, b_l, acc[nt], 0, 0, 0);
      acc[nt] = __builtin_amdgcn_mfma_f32_16x16x32_bf16(a_l, b_h, acc[nt], 0, 0, 0);
    }
  }
  unsigned char* lby = (unsigned char*)smem;
  float sv = sparse[c_dri[z]];
  float dr = 1.0f / (1.0f + expf(-sv));
  #pragma unroll
  for (int nt = 0; nt < 4; ++nt) {
    #pragma unroll
    for (int reg = 0; reg < 4; ++reg) {
      int lr = wid*16 + quad*4 + reg;
      int lc = nt*16 + l15;
      int ga = bx*64 + lr, gb = by*64 + lc;
      int on = (fabsf(acc[nt][reg]) > dr) && !(dg && (ga == gb));
      lby[lr*68 + lc] = (unsigned char)on;
    }
  }
  __syncthreads();
  if (tid < 64) {
    u64 w = 0;
    for (int c2 = 0; c2 < 64; ++c2) w |= ((u64)lby[tid*68 + c2]) << c2;
    bits[z*16384 + (bx*64 + tid)*16 + by] = w;
    if (dg && bx != by) {
      u64 wt = 0;
      for (int c2 = 0; c2 < 64; ++c2) wt |= ((u64)lby[c2*68 + tid]) << c2;
      bits[z*16384 + (by*64 + tid)*16 + bx] = wt;
    }
  }
}

// ---------- 3. mask rows: 8-deep pipelined bit-walk ----------
__global__ __launch_bounds__(64) void k_maskrows(const u64* __restrict__ bits, u64* __restrict__ mask,
                                                 u64* __restrict__ mask_wm, int* __restrict__ deg2,
                                                 u64* __restrict__ cmask) {
  int u = blockIdx.x;
  int i = u >> 10, a = u & 1023;
  int t = threadIdx.x;
  __shared__ u64 drow[16];
  if (t < 16) drow[t] = bits[i*16384 + a*16 + t];
  __syncthreads();
  int j = t >> 4, wl = t & 15;
  u64 out;
  if (j == i) {
    out = drow[wl];
  } else {
    const u64* S = bits + c_src[i*4 + j]*16384;
    out = 0;
    for (int w2 = 0; w2 < 16; ++w2) {
      u64 m = drow[w2];
      const u64* base = S + (size_t)w2*1024 + wl;
      while (m) {
        u64 v0 = 0, v1 = 0, v2 = 0, v3 = 0, v4 = 0, v5 = 0, v6 = 0, v7 = 0;
        int b = __builtin_ctzll(m); m &= m - 1; v0 = base[b*16];
        if (m) { b = __builtin_ctzll(m); m &= m - 1; v1 = base[b*16]; }
        if (m) { b = __builtin_ctzll(m); m &= m - 1; v2 = base[b*16]; }
        if (m) { b = __builtin_ctzll(m); m &= m - 1; v3 = base[b*16]; }
        if (m) { b = __builtin_ctzll(m); m &= m - 1; v4 = base[b*16]; }
        if (m) { b = __builtin_ctzll(m); m &= m - 1; v5 = base[b*16]; }
        if (m) { b = __builtin_ctzll(m); m &= m - 1; v6 = base[b*16]; }
        if (m) { b = __builtin_ctzll(m); m &= m - 1; v7 = base[b*16]; }
        out |= ((v0 | v1) | (v2 | v3)) | ((v4 | v5) | (v6 | v7));
      }
    }
  }
  mask[(size_t)u*64 + t] = out;
  mask_wm[(size_t)t*4096 + u] = out;
  u64 bal = __ballot(out != 0ULL);
  if (t == 0 && bal) atomicOr((unsigned long long*)&cmask[64 + (u >> 6)], bal);
  int cnt = __popcll(out);
  for (int off = 32; off > 0; off >>= 1) cnt += __shfl_down(cnt, off);
  if (t == 0) deg2[u] = cnt;
}

// ---------- 4. bit transpose -> maskT word-major + deg1 atomics + cmask[g=0] ----------
__global__ __launch_bounds__(256) void k_bittrans2(const u64* __restrict__ mask, u64* __restrict__ wmT,
                                                   int* __restrict__ deg1, u64* __restrict__ cmask) {
  __shared__ u64 tile[4096];   // 64 rows x 64 words = 32 KB
  int tI = blockIdx.x, tid = threadIdx.x;
  for (int e = tid; e < 4096; e += 256) tile[e] = mask[(size_t)tI*4096 + e];
  __syncthreads();
  int wv = tid >> 6, lane = tid & 63;
  int tJ0 = blockIdx.y*16;
  for (int j = 0; j < 4; ++j) {
    int tJ = tJ0 + wv*4 + j;
    u64 o = 0;
    #pragma unroll 8
    for (int k = 0; k < 64; ++k) o |= ((tile[k*64 + tJ] >> lane) & 1ULL) << k;
    wmT[(size_t)tI*4096 + tJ*64 + lane] = o;
    atomicAdd(&deg1[tJ*64 + lane], __popcll(o));
    u64 bal = __ballot(o != 0ULL);
    if (lane == 0 && bal) atomicOr((unsigned long long*)&cmask[tJ], 1ULL << tI);
  }
}

// ---------- 5. dense GEMM + fused B-prep: Z tile + nrm-scaled frag-major BT packs ----------
__global__ __launch_bounds__(256) void k_dense3(const short* __restrict__ Ah, const short* __restrict__ Al,
                                                const short* __restrict__ Bh, const short* __restrict__ Bl,
                                                float* __restrict__ Z, int KC,
                                                const int* __restrict__ deg1, const int* __restrict__ deg2,
                                                short* __restrict__ bph, short* __restrict__ bpl) {
  __shared__ float tile[64*65];
  int tid = threadIdx.x, lane = tid & 63, wid = tid >> 6;
  int quad = lane >> 4, l15 = lane & 15;
  int m0 = blockIdx.x*64, n0 = blockIdx.y*64;
  const s8v* ah = (const s8v*)Ah + ((size_t)((m0>>4) + wid))*KC*64 + lane;
  const s8v* al = (const s8v*)Al + ((size_t)((m0>>4) + wid))*KC*64 + lane;
  const s8v* bh0 = (const s8v*)Bh + ((size_t)((n0>>4) + 0))*KC*64 + lane;
  const s8v* bh1 = (const s8v*)Bh + ((size_t)((n0>>4) + 1))*KC*64 + lane;
  const s8v* bh2 = (const s8v*)Bh + ((size_t)((n0>>4) + 2))*KC*64 + lane;
  const s8v* bh3 = (const s8v*)Bh + ((size_t)((n0>>4) + 3))*KC*64 + lane;
  const s8v* bl0 = (const s8v*)Bl + ((size_t)((n0>>4) + 0))*KC*64 + lane;
  const s8v* bl1 = (const s8v*)Bl + ((size_t)((n0>>4) + 1))*KC*64 + lane;
  const s8v* bl2 = (const s8v*)Bl + ((size_t)((n0>>4) + 2))*KC*64 + lane;
  const s8v* bl3 = (const s8v*)Bl + ((size_t)((n0>>4) + 3))*KC*64 + lane;
  f4v acc[4];
  #pragma unroll
  for (int i = 0; i < 4; ++i) { acc[i][0]=0.f; acc[i][1]=0.f; acc[i][2]=0.f; acc[i][3]=0.f; }
  for (int c = 0; c < KC; ++c) {
    s8v a_h = ah[c*64];
    s8v a_l = al[c*64];
    acc[0] = __builtin_amdgcn_mfma_f32_16x16x32_bf16(a_h, bh0[c*64], acc[0], 0, 0, 0);
    acc[0] = __builtin_amdgcn_mfma_f32_16x16x32_bf16(a_h, bl0[c*64], acc[0], 0, 0, 0);
    acc[0] = __builtin_amdgcn_mfma_f32_16x16x32_bf16(a_l, bh0[c*64], acc[0], 0, 0, 0);
    acc[1] = __builtin_amdgcn_mfma_f32_16x16x32_bf16(a_h, bh1[c*64], acc[1], 0, 0, 0);
    acc[1] = __builtin_amdgcn_mfma_f32_16x16x32_bf16(a_h, bl1[c*64], acc[1], 0, 0, 0);
    acc[1] = __builtin_amdgcn_mfma_f32_16x16x32_bf16(a_l, bh1[c*64], acc[1], 0, 0, 0);
    acc[2] = __builtin_amdgcn_mfma_f32_16x16x32_bf16(a_h, bh2[c*64], acc[2], 0, 0, 0);
    acc[2] = __builtin_amdgcn_mfma_f32_16x16x32_bf16(a_h, bl2[c*64], acc[2], 0, 0, 0);
    acc[2] = __builtin_amdgcn_mfma_f32_16x16x32_bf16(a_l, bh2[c*64], acc[2], 0, 0, 0);
    acc[3] = __builtin_amdgcn_mfma_f32_16x16x32_bf16(a_h, bh3[c*64], acc[3], 0, 0, 0);
    acc[3] = __builtin_amdgcn_mfma_f32_16x16x32_bf16(a_h, bl3[c*64], acc[3], 0, 0, 0);
    acc[3] = __builtin_amdgcn_mfma_f32_16x16x32_bf16(a_l, bh3[c*64], acc[3], 0, 0, 0);
  }
  #pragma unroll
  for (int nt = 0; nt < 4; ++nt) {
    #pragma unroll
    for (int reg = 0; reg < 4; ++reg) {
      int rl = wid*16 + quad*4 + reg;
      int cl = nt*16 + l15;
      float v = acc[nt][reg];
      Z[(size_t)(m0+rl)*512 + n0 + cl] = v;
      tile[rl*65 + cl] = v;
    }
  }
  __syncthreads();
  const int* dg = (n0 < 256) ? deg1 : deg2;
  for (int e = tid; e < 4096; e += 256) {   // pack-major write order (coalesced)
    int j = e & 7, ln = (e >> 3) & 63, cp = (e >> 9) & 1, Tp = e >> 10;
    int q = ln >> 4, rr = ln & 15;
    int krow = cp*32 + q*8 + j;             // node-local row
    int d = dg[m0 + krow];
    float nr = d > 0 ? (1.0f / sqrtf((float)d)) : 0.0f;
    float v = tile[krow*65 + (Tp*16 + rr)] * nr;
    short h, l; split2(v, h, l);
    size_t off = (((size_t)((n0>>4)+Tp)*128 + (m0>>5)+cp)*64 + ln)*8 + j;
    bph[off] = h; bpl[off] = l;
  }
}

// ---------- 6. mask GEMM v3 + fused BN partial sums (round-9 measured best) ----------
__global__ __launch_bounds__(512) void k_mg3(const u64* __restrict__ wmT, const u64* __restrict__ wmR,
                                             const u64* __restrict__ cmask,
                                             const short* __restrict__ bph, const short* __restrict__ bpl,
                                             const float* __restrict__ Z,
                                             const int* __restrict__ deg1, const int* __restrict__ deg2,
                                             const float* __restrict__ biasA, const float* __restrict__ biasB,
                                             float* __restrict__ h, float* __restrict__ bnacc) {
  __shared__ s8v lut[256];   // byte -> 8 bf16 {0,1}
  __shared__ float tile[64*65];
  int tid = threadIdx.x;
  if (tid < 256) {
    s8v e;
    #pragma unroll
    for (int j = 0; j < 8; ++j) e[j] = ((tid >> j) & 1) ? (short)0x3F80 : (short)0;
    lut[tid] = e;
  }
  __syncthreads();
  int g = blockIdx.z;
  const u64* wm = g ? wmR : wmT;
  u64 cm = cmask[g*64 + blockIdx.x];
  int m0 = blockIdx.x*64, n0 = blockIdx.y*64;
  int lane = tid & 63, wid = tid >> 6, quad = lane >> 4, l15 = lane & 15;
  int nw = wid & 3, ks = wid >> 2;
  u64 cmw = ks ? (cm >> 32) : (cm & 0xffffffffULL);
  int kwb = ks << 5;
  int T = g*16 + (n0 >> 4) + nw;
  const s8v* BH = (const s8v*)bph + (size_t)T*128*64 + lane;
  const s8v* BL = (const s8v*)bpl + (size_t)T*128*64 + lane;
  f4v acc[4];
  #pragma unroll
  for (int i = 0; i < 4; ++i) { acc[i][0]=0.f; acc[i][1]=0.f; acc[i][2]=0.f; acc[i][3]=0.f; }
  s8v z8;
  #pragma unroll
  for (int j = 0; j < 8; ++j) z8[j] = 0;

  int kw = -1;
  u64 w0 = 0, w1 = 0, w2 = 0, w3 = 0;
  s8v b0h = z8, b0l = z8, b1h = z8, b1l = z8;
  if (cmw) {
    kw = kwb + __builtin_ctzll(cmw); cmw &= cmw - 1;
    const u64* wp = wm + (size_t)kw*4096 + m0;
    w0 = wp[l15]; w1 = wp[16 + l15]; w2 = wp[32 + l15]; w3 = wp[48 + l15];
    b0h = BH[(kw*2)*64];   b0l = BL[(kw*2)*64];
    b1h = BH[(kw*2+1)*64]; b1l = BL[(kw*2+1)*64];
  }
  while (kw >= 0) {
    int kwn = -1;
    u64 nw0 = 0, nw1 = 0, nw2 = 0, nw3 = 0;
    s8v nb0h = z8, nb0l = z8, nb1h = z8, nb1l = z8;
    if (cmw) {                                  // prefetch next chunk (mask words + B frags)
      kwn = kwb + __builtin_ctzll(cmw); cmw &= cmw - 1;
      const u64* wp = wm + (size_t)kwn*4096 + m0;
      nw0 = wp[l15]; nw1 = wp[16 + l15]; nw2 = wp[32 + l15]; nw3 = wp[48 + l15];
      nb0h = BH[(kwn*2)*64];   nb0l = BL[(kwn*2)*64];
      nb1h = BH[(kwn*2+1)*64]; nb1l = BL[(kwn*2+1)*64];
    }
    {
      unsigned sh = quad*8;
      s8v a0 = lut[(unsigned)(w0 >> sh) & 0xffu];
      s8v a1 = lut[(unsigned)(w1 >> sh) & 0xffu];
      s8v a2 = lut[(unsigned)(w2 >> sh) & 0xffu];
      s8v a3 = lut[(unsigned)(w3 >> sh) & 0xffu];
      acc[0] = __builtin_amdgcn_mfma_f32_16x16x32_bf16(a0, b0h, acc[0], 0, 0, 0);
      acc[0] = __builtin_amdgcn_mfma_f32_16x16x32_bf16(a0, b0l, acc[0], 0, 0, 0);
      acc[1] = __builtin_amdgcn_mfma_f32_16x16x32_bf16(a1, b0h, acc[1], 0, 0, 0);
      acc[1] = __builtin_amdgcn_mfma_f32_16x16x32_bf16(a1, b0l, acc[1], 0, 0, 0);
      acc[2] = __builtin_amdgcn_mfma_f32_16x16x32_bf16(a2, b0h, acc[2], 0, 0, 0);
      acc[2] = __builtin_amdgcn_mfma_f32_16x16x32_bf16(a2, b0l, acc[2], 0, 0, 0);
      acc[3] = __builtin_amdgcn_mfma_f32_16x16x32_bf16(a3, b0h, acc[3], 0, 0, 0);
      acc[3] = __builtin_amdgcn_mfma_f32_16x16x32_bf16(a3, b0l, acc[3], 0, 0, 0);
      sh = 32 + quad*8;
      a0 = lut[(unsigned)(w0 >> sh) & 0xffu];
      a1 = lut[(unsigned)(w1 >> sh) & 0xffu];
      a2 = lut[(unsigned)(w2 >> sh) & 0xffu];
      a3 = lut[(unsigned)(w3 >> sh) & 0xffu];
      acc[0] = __builtin_amdgcn_mfma_f32_16x16x32_bf16(a0, b1h, acc[0], 0, 0, 0);
      acc[0] = __builtin_amdgcn_mfma_f32_16x16x32_bf16(a0, b1l, acc[0], 0, 0, 0);
      acc[1] = __builtin_amdgcn_mfma_f32_16x16x32_bf16(a1, b1h, acc[1], 0, 0, 0);
      acc[1] = __builtin_amdgcn_mfma_f32_16x16x32_bf16(a1, b1l, acc[1], 0, 0, 0);
      acc[2] = __builtin_amdgcn_mfma_f32_16x16x32_bf16(a2, b1h, acc[2], 0, 0, 0);
      acc[2] = __builtin_amdgcn_mfma_f32_16x16x32_bf16(a2, b1l, acc[2], 0, 0, 0);
      acc[3] = __builtin_amdgcn_mfma_f32_16x16x32_bf16(a3, b1h, acc[3], 0, 0, 0);
      acc[3] = __builtin_amdgcn_mfma_f32_16x16x32_bf16(a3, b1l, acc[3], 0, 0, 0);
    }
    kw = kwn;
    w0 = nw0; w1 = nw1; w2 = nw2; w3 = nw3;
    b0h = nb0h; b0l = nb0l; b1h = nb1h; b1l = nb1l;
  }
  // combine K-halves through LDS; epilogue + BN partial sums by ks==0 waves
  int nl = nw*16 + l15;
  if (ks == 1) {
    #pragma unroll
    for (int mf = 0; mf < 4; ++mf) {
      #pragma unroll
      for (int reg = 0; reg < 4; ++reg)
        tile[(mf*16 + quad*4 + reg)*65 + nl] = acc[mf][reg];
    }
  }
  __syncthreads();
  if (ks == 0) {
    int n = n0 + nl;
    const int* dgp = g ? deg2 : deg1;
    float bn = (g ? biasB : biasA)[n];
    int zoff = g*256;
    float sv = 0.0f, qv = 0.0f;
    #pragma unroll
    for (int mf = 0; mf < 4; ++mf) {
      #pragma unroll
      for (int reg = 0; reg < 4; ++reg) {
        int v = m0 + mf*16 + quad*4 + reg;
        float s = acc[mf][reg] + tile[(mf*16 + quad*4 + reg)*65 + nl];
        int d = dgp[v];
        float sfac = 0.0f;
        if (d > 0) { float df = (float)d; sfac = (1.0f / sqrtf(df)) / df; }
        float val = Z[(size_t)v*512 + zoff + n] + sfac*s + bn;
        val = fmaxf(val, 0.0f);
        h[(size_t)v*512 + zoff + n] = val;
        sv += val; qv += val*val;
      }
    }
    // reduce over the 4 quads sharing column n
    sv += __shfl_down(sv, 32); qv += __shfl_down(qv, 32);
    sv += __shfl_down(sv, 16); qv += __shfl_down(qv, 16);
    if (quad == 0) {
      int col = zoff + n;
      atomicAdd(&bnacc[col*2 + 0], sv);
      atomicAdd(&bnacc[col*2 + 1], qv);
    }
  }
}

// ---------- 7. BN apply + split to frag-major hn packs (K=512) ----------
__global__ __launch_bounds__(256) void k_bnapply_split(const float* __restrict__ h, const float* __restrict__ acc,
                                                       const float* __restrict__ gamma, const float* __restrict__ beta,
                                                       short* __restrict__ hPh, short* __restrict__ hPl) {
  int i = blockIdx.x*256 + threadIdx.x;       // 524288 float4s
  float4 v = ((const float4*)h)[i];
  int r = i >> 7;
  int colb = (i & 127) * 4;
  float vv[4] = {v.x, v.y, v.z, v.w};
  short4 hh, ll;
  short* hp = (short*)&hh; short* lp = (short*)&ll;
  #pragma unroll
  for (int j = 0; j < 4; ++j) {
    int col = colb + j;
    float mean = acc[col*2] * (1.0f/4096.0f);
    float var  = acc[col*2 + 1] * (1.0f/4096.0f) - mean*mean;
    float inv  = rsqrtf(var + 1e-5f);
    float sc = gamma[col] * inv;
    float sh = beta[col] - mean * sc;
    split2(vv[j]*sc + sh, hp[j], lp[j]);
  }
  size_t off = packoff(r, colb, 16);
  ((short4*)hPh)[off >> 2] = hh;
  ((short4*)hPl)[off >> 2] = ll;
}

// ---------- 8. final: inline BN2 + readout + modality softmax mix ----------
__global__ __launch_bounds__(256) void k_final2(const float* __restrict__ h, const float* __restrict__ acc2,
                                                const float* __restrict__ gamma2, const float* __restrict__ beta2,
                                                const float* __restrict__ w_ro, const float* __restrict__ cl,
                                                float* __restrict__ out) {
  int node = blockIdx.x;
  int t = threadIdx.x, m = t >> 6, lane = t & 63;
  const float* row = h + (size_t)(m*1024 + node)*512;
  float a0 = 0.f, a1 = 0.f, a2 = 0.f, a3 = 0.f;
  for (int it = 0; it < 8; ++it) {
    int k = lane + it*64;
    float mean = acc2[k*2] * (1.0f/4096.0f);
    float var  = acc2[k*2 + 1] * (1.0f/4096.0f) - mean*mean;
    float inv  = rsqrtf(var + 1e-5f);
    float sc = gamma2[k] * inv;
    float sh = beta2[k] - mean * sc;
    float hv = row[k]*sc + sh;
    float4 w = ((const float4*)w_ro)[k];
    a0 += hv*w.x; a1 += hv*w.y; a2 += hv*w.z; a3 += hv*w.w;
  }
  for (int off = 32; off > 0; off >>= 1) {
    a0 += __shfl_down(a0, off); a1 += __shfl_down(a1, off);
    a2 += __shfl_down(a2, off); a3 += __shfl_down(a3, off);
  }
  __shared__ float part[4][4];
  if (lane == 0) { part[m][0]=a0; part[m][1]=a1; part[m][2]=a2; part[m][3]=a3; }
  __syncthreads();
  if (t < 4) {
    float c0 = cl[0], c1 = cl[1], c2 = cl[2], c3 = cl[3];
    float mx = fmaxf(fmaxf(c0,c1), fmaxf(c2,c3));
    float e0 = expf(c0-mx), e1 = expf(c1-mx), e2 = expf(c2-mx), e3 = expf(c3-mx);
    float inv = 1.0f/(e0+e1+e2+e3);
    float r = (e0*part[0][t] + e1*part[1][t] + e2*part[2][t] + e3*part[3][t]) * inv;
    out[node*4 + t] = r;
  }
}

extern "C" void kernel_launch(void* const* d_in, const int* in_sizes, int n_in,
                              void* d_out, int out_size, void* d_ws, size_t ws_size,
                              hipStream_t stream) {
  const float* features = (const float*)d_in[0];
  const float* sparse   = (const float*)d_in[1];
  const float* cmix     = (const float*)d_in[2];
  const float* wAC1 = (const float*)d_in[3];
  const float* bAC1 = (const float*)d_in[4];
  const float* wCA1 = (const float*)d_in[5];
  const float* bCA1 = (const float*)d_in[6];
  const float* wAC2 = (const float*)d_in[7];
  const float* bAC2 = (const float*)d_in[8];
  const float* wCA2 = (const float*)d_in[9];
  const float* bCA2 = (const float*)d_in[10];
  const float* gamma1 = (const float*)d_in[11];
  const float* beta1  = (const float*)d_in[12];
  const float* gamma2 = (const float*)d_in[13];
  const float* beta2  = (const float*)d_in[14];
  const float* w_ro   = (const float*)d_in[15];
  float* out = (float*)d_out;

  char* ws = (char*)d_ws;
  const size_t MB = 1024ull*1024ull, KB = 1024ull;
  u64*   bits    = (u64*)(ws + 0);               // 1.25 MB
  u64*   mask    = (u64*)(ws + 2*MB);            // 2 MB (row-major)
  u64*   mask_wm = (u64*)(ws + 4*MB);            // 2 MB (word-major)
  u64*   maskT_wm= (u64*)(ws + 6*MB);            // 2 MB (word-major)
  int*   deg1    = (int*)(ws + 8*MB);            // 16 KB  [zeroed by k_rownorm]
  float* bnacc1  = (float*)(ws + 8*MB + 16*KB);  // 4 KB   [zeroed by k_rownorm]
  float* bnacc2  = (float*)(ws + 8*MB + 20*KB);  // 4 KB   [zeroed by k_rownorm]
  u64*   cmask   = (u64*)(ws + 8*MB + 24*KB);    // 1 KB   [zeroed by k_rownorm]
  int*   deg2    = (int*)(ws + 8*MB + 28*KB);    // 16 KB
  short* WT1h  = (short*)(ws + 9*MB);            // 128 KB (frag-major pack)
  short* WT1l  = (short*)(ws + 9*MB + 128*KB);   // 128 KB
  short* WT2h  = (short*)(ws + 9*MB + 256*KB);   // 512 KB
  short* WT2l  = (short*)(ws + 9*MB + 768*KB);   // 512 KB
  short* yhP   = (short*)(ws + 11*MB);           // 1 MB (dead after corr3)
  short* ymP   = (short*)(ws + 12*MB);           // 1 MB
  short* ylP   = (short*)(ws + 13*MB);           // 1 MB
  short* fPh   = (short*)(ws + 14*MB);           // 1 MB (dead after L1 dense)
  short* fPl   = (short*)(ws + 15*MB);           // 1 MB
  short* hnPh  = (short*)(ws + 16*MB);           // 4 MB (frag-major, K=512)
  short* hnPl  = (short*)(ws + 20*MB);           // 4 MB
  short* BTh   = (short*)(ws + 24*MB);           // 4 MB (frag-major, distinct from hnP!)
  short* BTl   = (short*)(ws + 28*MB);           // 4 MB
  float* Z     = (float*)(ws + 32*MB);           // 8 MB
  float* h     = (float*)(ws + 40*MB);           // 8 MB (total 48 MB)

  // graph prep (memset folded into k_rownorm; weight prep folded into k_corr3 z=10,11)
  k_rownorm<<<dim3(4096), dim3(128), 0, stream>>>(features, yhP, ymP, ylP, fPh, fPl, deg1);
  k_corr3<<<dim3(16,16,12), dim3(256), 0, stream>>>(yhP, ymP, ylP, sparse, bits,
                                                    wAC1, wCA1, wAC2, wCA2, WT1h, WT1l, WT2h, WT2l);
  k_maskrows<<<dim3(4096), dim3(64), 0, stream>>>(bits, mask, mask_wm, deg2, cmask);
  k_bittrans2<<<dim3(64,4), dim3(256), 0, stream>>>(mask, maskT_wm, deg1, cmask);

  // layer 1:  h = relu(Z + sfac*(bits @ (nrm*Z)) + b)  [dense3 also emits BT packs]
  k_dense3<<<dim3(64,8), dim3(256), 0, stream>>>(fPh, fPl, WT1h, WT1l, Z, 4, deg1, deg2, BTh, BTl);
  k_mg3<<<dim3(64,4,2), dim3(512), 0, stream>>>(maskT_wm, mask_wm, cmask, BTh, BTl, Z,
                                                deg1, deg2, bAC1, bCA1, h, bnacc1);
  k_bnapply_split<<<dim3(2048), dim3(256), 0, stream>>>(h, bnacc1, gamma1, beta1, hnPh, hnPl);

  // layer 2
  k_dense3<<<dim3(64,8), dim3(256), 0, stream>>>(hnPh, hnPl, WT2h, WT2l, Z, 16, deg1, deg2, BTh, BTl);
  k_mg3<<<dim3(64,4,2), dim3(512), 0, stream>>>(maskT_wm, mask_wm, cmask, BTh, BTl, Z,
                                                deg1, deg2, bAC2, bCA2, h, bnacc2);

  // readout (BN2 folded inline)
  k_final2<<<dim3(1024), dim3(256), 0, stream>>>(h, bnacc2, gamma2, beta2, w_ro, cmix, out);
}

// Round 13
// 253.084 us; speedup vs baseline: 1.1702x; 1.0336x over previous
//
#include <hip/hip_runtime.h>

typedef unsigned long long u64;
typedef __attribute__((ext_vector_type(8))) short s8v;   // 8 bf16 = 4 VGPRs (MFMA A/B frag)
typedef __attribute__((ext_vector_type(4))) float f4v;   // MFMA C/D frag

__device__ __constant__ int c_pi[10]   = {0,1,2,3,0,1,2,3,3,3};
__device__ __constant__ int c_pj[10]   = {0,1,2,3,3,3,3,0,1,2};
__device__ __constant__ int c_dri[10]  = {1,5,8,10,4,7,9,4,7,9};
__device__ __constant__ int c_diag[10] = {1,1,1,1,0,0,0,0,0,0};
__device__ __constant__ int c_src[16]  = {-1,7,8,9,  4,-1,8,9,  5,5,-1,9,  6,6,6,-1};

// round-to-nearest bf16
__device__ inline unsigned short bf16rn(float v) {
  unsigned int u = __float_as_uint(v);
  unsigned int r = u + 0x7fffu + ((u >> 16) & 1u);
  return (unsigned short)(r >> 16);
}
__device__ inline void split2(float v, short& h, short& l) {
  unsigned short hs = bf16rn(v);
  float fh = __uint_as_float(((unsigned int)hs) << 16);
  h = (short)hs;
  l = (short)bf16rn(v - fh);
}
__device__ inline void split3(float v, short& h, short& m, short& l) {
  unsigned short hs = bf16rn(v);
  float fh = __uint_as_float(((unsigned int)hs) << 16);
  float r1 = v - fh;
  unsigned short ms = bf16rn(r1);
  float fm = __uint_as_float(((unsigned int)ms) << 16);
  h = (short)hs; m = (short)ms;
  l = (short)bf16rn(r1 - fm);
}

// fragment-major pack offset: row r, k-index k, KC = K/32 chunks
__device__ inline size_t packoff(int row, int k, int KC) {
  int T = row >> 4, rr = row & 15;
  int c = k >> 5, q = (k >> 3) & 3, j = k & 7;
  return (((size_t)T*KC + c)*64 + q*16 + rr)*8 + j;
}

// ---------- 1. center+normalize rows -> 3 base split packs; feature pack; fused ws-zeroing ----------
__global__ __launch_bounds__(128) void k_rownorm(const float* __restrict__ f,
                                                 short* __restrict__ yhP, short* __restrict__ ymP,
                                                 short* __restrict__ ylP,
                                                 short* __restrict__ fPh, short* __restrict__ fPl,
                                                 int* __restrict__ zbase) {
  int r = blockIdx.x, t = threadIdx.x;
  int gid = r*128 + t;
  if (gid < 6400) zbase[gid] = 0;        // deg1(4096) + bnacc1(1024) + bnacc2(1024) + cmask(256)
  __shared__ float red[128];
  float v = f[r*128 + t];
  red[t] = v; __syncthreads();
  for (int s = 64; s > 0; s >>= 1) { if (t < s) red[t] += red[t+s]; __syncthreads(); }
  float mean = red[0] * (1.0f/128.0f);
  __syncthreads();
  float xc = v - mean;
  red[t] = xc*xc; __syncthreads();
  for (int s = 64; s > 0; s >>= 1) { if (t < s) red[t] += red[t+s]; __syncthreads(); }
  float inv = 1.0f / sqrtf(red[0]);
  short h, m, l;
  split3(xc*inv, h, m, l);
  size_t o = packoff(r, t, 4);
  yhP[o] = h; ymP[o] = m; ylP[o] = l;
  short fh, fl; split2(v, fh, fl);
  fPh[o] = fh; fPl[o] = fl;
}

// ---------- 2. correlation bit blocks (z<10) + weight prep (z=10,11) ----------
__global__ __launch_bounds__(256) void k_corr3(const short* __restrict__ yhP, const short* __restrict__ ymP,
                                               const short* __restrict__ ylP,
                                               const float* __restrict__ sparse, u64* __restrict__ bits,
                                               const float* __restrict__ wAC1, const float* __restrict__ wCA1,
                                               const float* __restrict__ wAC2, const float* __restrict__ wCA2,
                                               short* __restrict__ w1h, short* __restrict__ w1l,
                                               short* __restrict__ w2h, short* __restrict__ w2l) {
  __shared__ char smem[64*65*4];   // 16.6 KB: float lds (prepWT) or uchar lby (corr)
  int z = blockIdx.z;
  int bx = blockIdx.x, by = blockIdx.y;
  int tid = threadIdx.x;
  if (z >= 10) {                   // fused weight prep
    int zz = z - 10;               // 0: layer2 (K=512), 1: layer1 (K=128)
    int K = zz ? 128 : 512;
    if (by >= 8 || bx >= (K >> 6)) return;
    const float* Wa = zz ? wAC1 : wAC2;
    const float* Wb = zz ? wCA1 : wCA2;
    short* wph = zz ? w1h : w2h;
    short* wpl = zz ? w1l : w2l;
    float* lds = (float*)smem;
    int k0 = bx*64, n0 = by*64;
    const float* W = (n0 < 256) ? Wa : Wb;
    int nc0 = n0 & 255;
    for (int e = tid; e < 4096; e += 256) {
      int r = e >> 6, c = e & 63;
      lds[r*65 + c] = W[(size_t)(k0+r)*256 + nc0 + c];
    }
    __syncthreads();
    int KC = K >> 5;
    for (int e = tid; e < 4096; e += 256) {
      int j = e & 7, ln = (e >> 3) & 63, cp = (e >> 9) & 1, Tp = e >> 10;
      int q = ln >> 4, rr = ln & 15;
      float v = lds[(cp*32 + q*8 + j)*65 + (Tp*16 + rr)];
      short h, l; split2(v, h, l);
      size_t off = (((size_t)((n0>>4)+Tp)*KC + (k0>>5)+cp)*64 + ln)*8 + j;
      wph[off] = h; wpl[off] = l;
    }
    return;
  }
  int dg = c_diag[z];
  if (dg && by < bx) return;
  int a0 = c_pi[z]*1024 + bx*64;
  int b0 = c_pj[z]*1024 + by*64;
  int lane = tid & 63, wid = tid >> 6;
  int quad = lane >> 4, l15 = lane & 15;
  const s8v* AH = (const s8v*)yhP + ((size_t)((a0>>4) + wid))*4*64 + lane;
  const s8v* AM = (const s8v*)ymP + ((size_t)((a0>>4) + wid))*4*64 + lane;
  const s8v* AL = (const s8v*)ylP + ((size_t)((a0>>4) + wid))*4*64 + lane;
  const s8v* BH = (const s8v*)yhP + ((size_t)(b0>>4))*4*64 + lane;
  const s8v* BM = (const s8v*)ymP + ((size_t)(b0>>4))*4*64 + lane;
  const s8v* BL = (const s8v*)ylP + ((size_t)(b0>>4))*4*64 + lane;
  f4v acc[4];
  #pragma unroll
  for (int i = 0; i < 4; ++i) { acc[i][0]=0.f; acc[i][1]=0.f; acc[i][2]=0.f; acc[i][3]=0.f; }
  for (int c = 0; c < 4; ++c) {
    s8v a_h = AH[c*64];
    s8v a_m = AM[c*64];
    s8v a_l = AL[c*64];
    #pragma unroll
    for (int nt = 0; nt < 4; ++nt) {
      s8v b_h = BH[(nt*4 + c)*64];
      s8v b_m = BM[(nt*4 + c)*64];
      s8v b_l = BL[(nt*4 + c)*64];
      acc[nt] = __builtin_amdgcn_mfma_f32_16x16x32_bf16(a_h, b_h, acc[nt], 0, 0, 0);
      acc[nt] = __builtin_amdgcn_mfma_f32_16x16x32_bf16(a_m, b_m, acc[nt], 0, 0, 0);
      acc[nt] = __builtin_amdgcn_mfma_f32_16x16x32_bf16(a_h, b_m, acc[nt], 0, 0, 0);
      acc[nt] = __builtin_amdgcn_mfma_f32_16x16x32_bf16(a_m, b_h, acc[nt], 0, 0, 0);
      acc[nt] = __builtin_amdgcn_mfma_f32_16x16x32_bf16(a_h, b_l, acc[nt], 0, 0, 0);
      acc[nt] = __builtin_amdgcn_mfma_f32_16x16x32_bf16(a_l, b_h, acc[nt], 0, 0, 0);
    }
  }
  unsigned char* lby = (unsigned char*)smem;
  float sv = sparse[c_dri[z]];
  float dr = 1.0f / (1.0f + expf(-sv));
  #pragma unroll
  for (int nt = 0; nt < 4; ++nt) {
    #pragma unroll
    for (int reg = 0; reg < 4; ++reg) {
      int lr = wid*16 + quad*4 + reg;
      int lc = nt*16 + l15;
      int ga = bx*64 + lr, gb = by*64 + lc;
      int on = (fabsf(acc[nt][reg]) > dr) && !(dg && (ga == gb));
      lby[lr*68 + lc] = (unsigned char)on;
    }
  }
  __syncthreads();
  if (tid < 64) {
    u64 w = 0;
    for (int c2 = 0; c2 < 64; ++c2) w |= ((u64)lby[tid*68 + c2]) << c2;
    bits[z*16384 + (bx*64 + tid)*16 + by] = w;
    if (dg && bx != by) {
      u64 wt = 0;
      for (int c2 = 0; c2 < 64; ++c2) wt |= ((u64)lby[c2*68 + tid]) << c2;
      bits[z*16384 + (by*64 + tid)*16 + bx] = wt;
    }
  }
}

// ---------- 3. mask rows: 8-deep pipelined bit-walk ----------
__global__ __launch_bounds__(64) void k_maskrows(const u64* __restrict__ bits, u64* __restrict__ mask,
                                                 u64* __restrict__ mask_wm, int* __restrict__ deg2,
                                                 u64* __restrict__ cmask) {
  int u = blockIdx.x;
  int i = u >> 10, a = u & 1023;
  int t = threadIdx.x;
  __shared__ u64 drow[16];
  if (t < 16) drow[t] = bits[i*16384 + a*16 + t];
  __syncthreads();
  int j = t >> 4, wl = t & 15;
  u64 out;
  if (j == i) {
    out = drow[wl];
  } else {
    const u64* S = bits + c_src[i*4 + j]*16384;
    out = 0;
    for (int w2 = 0; w2 < 16; ++w2) {
      u64 m = drow[w2];
      const u64* base = S + (size_t)w2*1024 + wl;
      while (m) {
        u64 v0 = 0, v1 = 0, v2 = 0, v3 = 0, v4 = 0, v5 = 0, v6 = 0, v7 = 0;
        int b = __builtin_ctzll(m); m &= m - 1; v0 = base[b*16];
        if (m) { b = __builtin_ctzll(m); m &= m - 1; v1 = base[b*16]; }
        if (m) { b = __builtin_ctzll(m); m &= m - 1; v2 = base[b*16]; }
        if (m) { b = __builtin_ctzll(m); m &= m - 1; v3 = base[b*16]; }
        if (m) { b = __builtin_ctzll(m); m &= m - 1; v4 = base[b*16]; }
        if (m) { b = __builtin_ctzll(m); m &= m - 1; v5 = base[b*16]; }
        if (m) { b = __builtin_ctzll(m); m &= m - 1; v6 = base[b*16]; }
        if (m) { b = __builtin_ctzll(m); m &= m - 1; v7 = base[b*16]; }
        out |= ((v0 | v1) | (v2 | v3)) | ((v4 | v5) | (v6 | v7));
      }
    }
  }
  mask[(size_t)u*64 + t] = out;
  mask_wm[(size_t)t*4096 + u] = out;
  u64 bal = __ballot(out != 0ULL);
  if (t == 0 && bal) atomicOr((unsigned long long*)&cmask[64 + (u >> 6)], bal);
  int cnt = __popcll(out);
  for (int off = 32; off > 0; off >>= 1) cnt += __shfl_down(cnt, off);
  if (t == 0) deg2[u] = cnt;
}

// ---------- 4. bit transpose -> maskT word-major + deg1 atomics + cmask[g=0] ----------
__global__ __launch_bounds__(256) void k_bittrans2(const u64* __restrict__ mask, u64* __restrict__ wmT,
                                                   int* __restrict__ deg1, u64* __restrict__ cmask) {
  __shared__ u64 tile[4096];   // 64 rows x 64 words = 32 KB
  int tI = blockIdx.x, tid = threadIdx.x;
  for (int e = tid; e < 4096; e += 256) tile[e] = mask[(size_t)tI*4096 + e];
  __syncthreads();
  int wv = tid >> 6, lane = tid & 63;
  int tJ0 = blockIdx.y*16;
  for (int j = 0; j < 4; ++j) {
    int tJ = tJ0 + wv*4 + j;
    u64 o = 0;
    #pragma unroll 8
    for (int k = 0; k < 64; ++k) o |= ((tile[k*64 + tJ] >> lane) & 1ULL) << k;
    wmT[(size_t)tI*4096 + tJ*64 + lane] = o;
    atomicAdd(&deg1[tJ*64 + lane], __popcll(o));
    u64 bal = __ballot(o != 0ULL);
    if (lane == 0 && bal) atomicOr((unsigned long long*)&cmask[tJ], 1ULL << tI);
  }
}

// ---------- 5. dense GEMM + fused B-prep: Z tile + nrm-scaled frag-major BT pack (hi only) ----------
__global__ __launch_bounds__(256) void k_dense3(const short* __restrict__ Ah, const short* __restrict__ Al,
                                                const short* __restrict__ Bh, const short* __restrict__ Bl,
                                                float* __restrict__ Z, int KC,
                                                const int* __restrict__ deg1, const int* __restrict__ deg2,
                                                short* __restrict__ bph) {
  __shared__ float tile[64*65];
  int tid = threadIdx.x, lane = tid & 63, wid = tid >> 6;
  int quad = lane >> 4, l15 = lane & 15;
  int m0 = blockIdx.x*64, n0 = blockIdx.y*64;
  const s8v* ah = (const s8v*)Ah + ((size_t)((m0>>4) + wid))*KC*64 + lane;
  const s8v* al = (const s8v*)Al + ((size_t)((m0>>4) + wid))*KC*64 + lane;
  const s8v* bh0 = (const s8v*)Bh + ((size_t)((n0>>4) + 0))*KC*64 + lane;
  const s8v* bh1 = (const s8v*)Bh + ((size_t)((n0>>4) + 1))*KC*64 + lane;
  const s8v* bh2 = (const s8v*)Bh + ((size_t)((n0>>4) + 2))*KC*64 + lane;
  const s8v* bh3 = (const s8v*)Bh + ((size_t)((n0>>4) + 3))*KC*64 + lane;
  const s8v* bl0 = (const s8v*)Bl + ((size_t)((n0>>4) + 0))*KC*64 + lane;
  const s8v* bl1 = (const s8v*)Bl + ((size_t)((n0>>4) + 1))*KC*64 + lane;
  const s8v* bl2 = (const s8v*)Bl + ((size_t)((n0>>4) + 2))*KC*64 + lane;
  const s8v* bl3 = (const s8v*)Bl + ((size_t)((n0>>4) + 3))*KC*64 + lane;
  f4v acc[4];
  #pragma unroll
  for (int i = 0; i < 4; ++i) { acc[i][0]=0.f; acc[i][1]=0.f; acc[i][2]=0.f; acc[i][3]=0.f; }
  for (int c = 0; c < KC; ++c) {
    s8v a_h = ah[c*64];
    s8v a_l = al[c*64];
    acc[0] = __builtin_amdgcn_mfma_f32_16x16x32_bf16(a_h, bh0[c*64], acc[0], 0, 0, 0);
    acc[0] = __builtin_amdgcn_mfma_f32_16x16x32_bf16(a_h, bl0[c*64], acc[0], 0, 0, 0);
    acc[0] = __builtin_amdgcn_mfma_f32_16x16x32_bf16(a_l, bh0[c*64], acc[0], 0, 0, 0);
    acc[1] = __builtin_amdgcn_mfma_f32_16x16x32_bf16(a_h, bh1[c*64], acc[1], 0, 0, 0);
    acc[1] = __builtin_amdgcn_mfma_f32_16x16x32_bf16(a_h, bl1[c*64], acc[1], 0, 0, 0);
    acc[1] = __builtin_amdgcn_mfma_f32_16x16x32_bf16(a_l, bh1[c*64], acc[1], 0, 0, 0);
    acc[2] = __builtin_amdgcn_mfma_f32_16x16x32_bf16(a_h, bh2[c*64], acc[2], 0, 0, 0);
    acc[2] = __builtin_amdgcn_mfma_f32_16x16x32_bf16(a_h, bl2[c*64], acc[2], 0, 0, 0);
    acc[2] = __builtin_amdgcn_mfma_f32_16x16x32_bf16(a_l, bh2[c*64], acc[2], 0, 0, 0);
    acc[3] = __builtin_amdgcn_mfma_f32_16x16x32_bf16(a_h, bh3[c*64], acc[3], 0, 0, 0);
    acc[3] = __builtin_amdgcn_mfma_f32_16x16x32_bf16(a_h, bl3[c*64], acc[3], 0, 0, 0);
    acc[3] = __builtin_amdgcn_mfma_f32_16x16x32_bf16(a_l, bh3[c*64], acc[3], 0, 0, 0);
  }
  #pragma unroll
  for (int nt = 0; nt < 4; ++nt) {
    #pragma unroll
    for (int reg = 0; reg < 4; ++reg) {
      int rl = wid*16 + quad*4 + reg;
      int cl = nt*16 + l15;
      float v = acc[nt][reg];
      Z[(size_t)(m0+rl)*512 + n0 + cl] = v;
      tile[rl*65 + cl] = v;
    }
  }
  __syncthreads();
  const int* dg = (n0 < 256) ? deg1 : deg2;
  for (int e = tid; e < 4096; e += 256) {   // pack-major write order (coalesced), hi only
    int j = e & 7, ln = (e >> 3) & 63, cp = (e >> 9) & 1, Tp = e >> 10;
    int q = ln >> 4, rr = ln & 15;
    int krow = cp*32 + q*8 + j;             // node-local row
    int d = dg[m0 + krow];
    float nr = d > 0 ? (1.0f / sqrtf((float)d)) : 0.0f;
    float v = tile[krow*65 + (Tp*16 + rr)] * nr;
    size_t off = (((size_t)((n0>>4)+Tp)*128 + (m0>>5)+cp)*64 + ln)*8 + j;
    bph[off] = (short)bf16rn(v);
  }
}

// ---------- 6. mask GEMM v3h: hi-only B (half loads, half MFMAs) + fused BN partial sums ----------
// error analysis: s = bits@(nrm*Z), |Δs| <= 2^-9 * Σ|nrm*Z| ~ 0.01; val += sfac*Δs ~ 1e-5 -> negligible
__global__ __launch_bounds__(512) void k_mg3(const u64* __restrict__ wmT, const u64* __restrict__ wmR,
                                             const u64* __restrict__ cmask,
                                             const short* __restrict__ bph,
                                             const float* __restrict__ Z,
                                             const int* __restrict__ deg1, const int* __restrict__ deg2,
                                             const float* __restrict__ biasA, const float* __restrict__ biasB,
                                             float* __restrict__ h, float* __restrict__ bnacc) {
  __shared__ s8v lut[256];   // byte -> 8 bf16 {0,1}
  __shared__ float tile[64*65];
  int tid = threadIdx.x;
  if (tid < 256) {
    s8v e;
    #pragma unroll
    for (int j = 0; j < 8; ++j) e[j] = ((tid >> j) & 1) ? (short)0x3F80 : (short)0;
    lut[tid] = e;
  }
  __syncthreads();
  int g = blockIdx.z;
  const u64* wm = g ? wmR : wmT;
  u64 cm = cmask[g*64 + blockIdx.x];
  int m0 = blockIdx.x*64, n0 = blockIdx.y*64;
  int lane = tid & 63, wid = tid >> 6, quad = lane >> 4, l15 = lane & 15;
  int nw = wid & 3, ks = wid >> 2;
  u64 cmw = ks ? (cm >> 32) : (cm & 0xffffffffULL);
  int kwb = ks << 5;
  int T = g*16 + (n0 >> 4) + nw;
  const s8v* BH = (const s8v*)bph + (size_t)T*128*64 + lane;
  f4v acc[4];
  #pragma unroll
  for (int i = 0; i < 4; ++i) { acc[i][0]=0.f; acc[i][1]=0.f; acc[i][2]=0.f; acc[i][3]=0.f; }
  s8v z8;
  #pragma unroll
  for (int j = 0; j < 8; ++j) z8[j] = 0;

  int kw = -1;
  u64 w0 = 0, w1 = 0, w2 = 0, w3 = 0;
  s8v b0h = z8, b1h = z8;
  if (cmw) {
    kw = kwb + __builtin_ctzll(cmw); cmw &= cmw - 1;
    const u64* wp = wm + (size_t)kw*4096 + m0;
    w0 = wp[l15]; w1 = wp[16 + l15]; w2 = wp[32 + l15]; w3 = wp[48 + l15];
    b0h = BH[(kw*2)*64];
    b1h = BH[(kw*2+1)*64];
  }
  while (kw >= 0) {
    int kwn = -1;
    u64 nw0 = 0, nw1 = 0, nw2 = 0, nw3 = 0;
    s8v nb0h = z8, nb1h = z8;
    if (cmw) {                                  // prefetch next chunk (mask words + B frags)
      kwn = kwb + __builtin_ctzll(cmw); cmw &= cmw - 1;
      const u64* wp = wm + (size_t)kwn*4096 + m0;
      nw0 = wp[l15]; nw1 = wp[16 + l15]; nw2 = wp[32 + l15]; nw3 = wp[48 + l15];
      nb0h = BH[(kwn*2)*64];
      nb1h = BH[(kwn*2+1)*64];
    }
    {
      unsigned sh = quad*8;
      s8v a0 = lut[(unsigned)(w0 >> sh) & 0xffu];
      s8v a1 = lut[(unsigned)(w1 >> sh) & 0xffu];
      s8v a2 = lut[(unsigned)(w2 >> sh) & 0xffu];
      s8v a3 = lut[(unsigned)(w3 >> sh) & 0xffu];
      acc[0] = __builtin_amdgcn_mfma_f32_16x16x32_bf16(a0, b0h, acc[0], 0, 0, 0);
      acc[1] = __builtin_amdgcn_mfma_f32_16x16x32_bf16(a1, b0h, acc[1], 0, 0, 0);
      acc[2] = __builtin_amdgcn_mfma_f32_16x16x32_bf16(a2, b0h, acc[2], 0, 0, 0);
      acc[3] = __builtin_amdgcn_mfma_f32_16x16x32_bf16(a3, b0h, acc[3], 0, 0, 0);
      sh = 32 + quad*8;
      a0 = lut[(unsigned)(w0 >> sh) & 0xffu];
      a1 = lut[(unsigned)(w1 >> sh) & 0xffu];
      a2 = lut[(unsigned)(w2 >> sh) & 0xffu];
      a3 = lut[(unsigned)(w3 >> sh) & 0xffu];
      acc[0] = __builtin_amdgcn_mfma_f32_16x16x32_bf16(a0, b1h, acc[0], 0, 0, 0);
      acc[1] = __builtin_amdgcn_mfma_f32_16x16x32_bf16(a1, b1h, acc[1], 0, 0, 0);
      acc[2] = __builtin_amdgcn_mfma_f32_16x16x32_bf16(a2, b1h, acc[2], 0, 0, 0);
      acc[3] = __builtin_amdgcn_mfma_f32_16x16x32_bf16(a3, b1h, acc[3], 0, 0, 0);
    }
    kw = kwn;
    w0 = nw0; w1 = nw1; w2 = nw2; w3 = nw3;
    b0h = nb0h; b1h = nb1h;
  }
  // combine K-halves through LDS; epilogue + BN partial sums by ks==0 waves
  int nl = nw*16 + l15;
  if (ks == 1) {
    #pragma unroll
    for (int mf = 0; mf < 4; ++mf) {
      #pragma unroll
      for (int reg = 0; reg < 4; ++reg)
        tile[(mf*16 + quad*4 + reg)*65 + nl] = acc[mf][reg];
    }
  }
  __syncthreads();
  if (ks == 0) {
    int n = n0 + nl;
    const int* dgp = g ? deg2 : deg1;
    float bn = (g ? biasB : biasA)[n];
    int zoff = g*256;
    float sv = 0.0f, qv = 0.0f;
    #pragma unroll
    for (int mf = 0; mf < 4; ++mf) {
      #pragma unroll
      for (int reg = 0; reg < 4; ++reg) {
        int v = m0 + mf*16 + quad*4 + reg;
        float s = acc[mf][reg] + tile[(mf*16 + quad*4 + reg)*65 + nl];
        int d = dgp[v];
        float sfac = 0.0f;
        if (d > 0) { float df = (float)d; sfac = (1.0f / sqrtf(df)) / df; }
        float val = Z[(size_t)v*512 + zoff + n] + sfac*s + bn;
        val = fmaxf(val, 0.0f);
        h[(size_t)v*512 + zoff + n] = val;
        sv += val; qv += val*val;
      }
    }
    // reduce over the 4 quads sharing column n
    sv += __shfl_down(sv, 32); qv += __shfl_down(qv, 32);
    sv += __shfl_down(sv, 16); qv += __shfl_down(qv, 16);
    if (quad == 0) {
      int col = zoff + n;
      atomicAdd(&bnacc[col*2 + 0], sv);
      atomicAdd(&bnacc[col*2 + 1], qv);
    }
  }
}

// ---------- 7. BN apply + split to frag-major hn packs (K=512) ----------
__global__ __launch_bounds__(256) void k_bnapply_split(const float* __restrict__ h, const float* __restrict__ acc,
                                                       const float* __restrict__ gamma, const float* __restrict__ beta,
                                                       short* __restrict__ hPh, short* __restrict__ hPl) {
  int i = blockIdx.x*256 + threadIdx.x;       // 524288 float4s
  float4 v = ((const float4*)h)[i];
  int r = i >> 7;
  int colb = (i & 127) * 4;
  float vv[4] = {v.x, v.y, v.z, v.w};
  short4 hh, ll;
  short* hp = (short*)&hh; short* lp = (short*)&ll;
  #pragma unroll
  for (int j = 0; j < 4; ++j) {
    int col = colb + j;
    float mean = acc[col*2] * (1.0f/4096.0f);
    float var  = acc[col*2 + 1] * (1.0f/4096.0f) - mean*mean;
    float inv  = rsqrtf(var + 1e-5f);
    float sc = gamma[col] * inv;
    float sh = beta[col] - mean * sc;
    split2(vv[j]*sc + sh, hp[j], lp[j]);
  }
  size_t off = packoff(r, colb, 16);
  ((short4*)hPh)[off >> 2] = hh;
  ((short4*)hPl)[off >> 2] = ll;
}

// ---------- 8. final: inline BN2 + readout + modality softmax mix ----------
__global__ __launch_bounds__(256) void k_final2(const float* __restrict__ h, const float* __restrict__ acc2,
                                                const float* __restrict__ gamma2, const float* __restrict__ beta2,
                                                const float* __restrict__ w_ro, const float* __restrict__ cl,
                                                float* __restrict__ out) {
  int node = blockIdx.x;
  int t = threadIdx.x, m = t >> 6, lane = t & 63;
  const float* row = h + (size_t)(m*1024 + node)*512;
  float a0 = 0.f, a1 = 0.f, a2 = 0.f, a3 = 0.f;
  for (int it = 0; it < 8; ++it) {
    int k = lane + it*64;
    float mean = acc2[k*2] * (1.0f/4096.0f);
    float var  = acc2[k*2 + 1] * (1.0f/4096.0f) - mean*mean;
    float inv  = rsqrtf(var + 1e-5f);
    float sc = gamma2[k] * inv;
    float sh = beta2[k] - mean * sc;
    float hv = row[k]*sc + sh;
    float4 w = ((const float4*)w_ro)[k];
    a0 += hv*w.x; a1 += hv*w.y; a2 += hv*w.z; a3 += hv*w.w;
  }
  for (int off = 32; off > 0; off >>= 1) {
    a0 += __shfl_down(a0, off); a1 += __shfl_down(a1, off);
    a2 += __shfl_down(a2, off); a3 += __shfl_down(a3, off);
  }
  __shared__ float part[4][4];
  if (lane == 0) { part[m][0]=a0; part[m][1]=a1; part[m][2]=a2; part[m][3]=a3; }
  __syncthreads();
  if (t < 4) {
    float c0 = cl[0], c1 = cl[1], c2 = cl[2], c3 = cl[3];
    float mx = fmaxf(fmaxf(c0,c1), fmaxf(c2,c3));
    float e0 = expf(c0-mx), e1 = expf(c1-mx), e2 = expf(c2-mx), e3 = expf(c3-mx);
    float inv = 1.0f/(e0+e1+e2+e3);
    float r = (e0*part[0][t] + e1*part[1][t] + e2*part[2][t] + e3*part[3][t]) * inv;
    out[node*4 + t] = r;
  }
}

extern "C" void kernel_launch(void* const* d_in, const int* in_sizes, int n_in,
                              void* d_out, int out_size, void* d_ws, size_t ws_size,
                              hipStream_t stream) {
  const float* features = (const float*)d_in[0];
  const float* sparse   = (const float*)d_in[1];
  const float* cmix     = (const float*)d_in[2];
  const float* wAC1 = (const float*)d_in[3];
  const float* bAC1 = (const float*)d_in[4];
  const float* wCA1 = (const float*)d_in[5];
  const float* bCA1 = (const float*)d_in[6];
  const float* wAC2 = (const float*)d_in[7];
  const float* bAC2 = (const float*)d_in[8];
  const float* wCA2 = (const float*)d_in[9];
  const float* bCA2 = (const float*)d_in[10];
  const float* gamma1 = (const float*)d_in[11];
  const float* beta1  = (const float*)d_in[12];
  const float* gamma2 = (const float*)d_in[13];
  const float* beta2  = (const float*)d_in[14];
  const float* w_ro   = (const float*)d_in[15];
  float* out = (float*)d_out;

  char* ws = (char*)d_ws;
  const size_t MB = 1024ull*1024ull, KB = 1024ull;
  u64*   bits    = (u64*)(ws + 0);               // 1.25 MB
  u64*   mask    = (u64*)(ws + 2*MB);            // 2 MB (row-major)
  u64*   mask_wm = (u64*)(ws + 4*MB);            // 2 MB (word-major)
  u64*   maskT_wm= (u64*)(ws + 6*MB);            // 2 MB (word-major)
  int*   deg1    = (int*)(ws + 8*MB);            // 16 KB  [zeroed by k_rownorm]
  float* bnacc1  = (float*)(ws + 8*MB + 16*KB);  // 4 KB   [zeroed by k_rownorm]
  float* bnacc2  = (float*)(ws + 8*MB + 20*KB);  // 4 KB   [zeroed by k_rownorm]
  u64*   cmask   = (u64*)(ws + 8*MB + 24*KB);    // 1 KB   [zeroed by k_rownorm]
  int*   deg2    = (int*)(ws + 8*MB + 28*KB);    // 16 KB
  short* WT1h  = (short*)(ws + 9*MB);            // 128 KB (frag-major pack)
  short* WT1l  = (short*)(ws + 9*MB + 128*KB);   // 128 KB
  short* WT2h  = (short*)(ws + 9*MB + 256*KB);   // 512 KB
  short* WT2l  = (short*)(ws + 9*MB + 768*KB);   // 512 KB
  short* yhP   = (short*)(ws + 11*MB);           // 1 MB (dead after corr3)
  short* ymP   = (short*)(ws + 12*MB);           // 1 MB
  short* ylP   = (short*)(ws + 13*MB);           // 1 MB
  short* fPh   = (short*)(ws + 14*MB);           // 1 MB (dead after L1 dense)
  short* fPl   = (short*)(ws + 15*MB);           // 1 MB
  short* hnPh  = (short*)(ws + 16*MB);           // 4 MB (frag-major, K=512)
  short* hnPl  = (short*)(ws + 20*MB);           // 4 MB
  short* BTh   = (short*)(ws + 24*MB);           // 4 MB (frag-major hi pack, distinct from hnP)
  float* Z     = (float*)(ws + 32*MB);           // 8 MB
  float* h     = (float*)(ws + 40*MB);           // 8 MB (total 48 MB)

  // graph prep (memset folded into k_rownorm; weight prep folded into k_corr3 z=10,11)
  k_rownorm<<<dim3(4096), dim3(128), 0, stream>>>(features, yhP, ymP, ylP, fPh, fPl, deg1);
  k_corr3<<<dim3(16,16,12), dim3(256), 0, stream>>>(yhP, ymP, ylP, sparse, bits,
                                                    wAC1, wCA1, wAC2, wCA2, WT1h, WT1l, WT2h, WT2l);
  k_maskrows<<<dim3(4096), dim3(64), 0, stream>>>(bits, mask, mask_wm, deg2, cmask);
  k_bittrans2<<<dim3(64,4), dim3(256), 0, stream>>>(mask, maskT_wm, deg1, cmask);

  // layer 1:  h = relu(Z + sfac*(bits @ (nrm*Z)) + b)  [dense3 also emits BT hi pack]
  k_dense3<<<dim3(64,8), dim3(256), 0, stream>>>(fPh, fPl, WT1h, WT1l, Z, 4, deg1, deg2, BTh);
  k_mg3<<<dim3(64,4,2), dim3(512), 0, stream>>>(maskT_wm, mask_wm, cmask, BTh, Z,
                                                deg1, deg2, bAC1, bCA1, h, bnacc1);
  k_bnapply_split<<<dim3(2048), dim3(256), 0, stream>>>(h, bnacc1, gamma1, beta1, hnPh, hnPl);

  // layer 2
  k_dense3<<<dim3(64,8), dim3(256), 0, stream>>>(hnPh, hnPl, WT2h, WT2l, Z, 16, deg1, deg2, BTh);
  k_mg3<<<dim3(64,4,2), dim3(512), 0, stream>>>(maskT_wm, mask_wm, cmask, BTh, Z,
                                                deg1, deg2, bAC2, bCA2, h, bnacc2);

  // readout (BN2 folded inline)
  k_final2<<<dim3(1024), dim3(256), 0, stream>>>(h, bnacc2, gamma2, beta2, w_ro, cmix, out);
}